// Round 3
// baseline (384.043 us; speedup 1.0000x reference)
//
#include <hip/hip_runtime.h>

#define N_NODES 50000
#define N_EDGES 600000
#define NPART 196   // ceil(50000/256)

using f32x2  = __attribute__((ext_vector_type(2))) float;
using f32x4  = __attribute__((ext_vector_type(4))) float;
using bf16x8 = __attribute__((ext_vector_type(8))) short;

__device__ inline short f2bf(float f) {
    uint32_t u = __builtin_bit_cast(uint32_t, f);
    uint32_t r = (u + 0x7FFFu + ((u >> 16) & 1u)) >> 16;
    return (short)r;
}
__device__ inline float bf2f(short h) {
    uint32_t u = ((uint32_t)(uint16_t)h) << 16;
    return __builtin_bit_cast(float, u);
}

// ---------------------------------------------------------------- CSR build

__global__ void count_kernel(const int* __restrict__ dst, int* __restrict__ cnt) {
    int e = blockIdx.x * blockDim.x + threadIdx.x;
    if (e < N_EDGES) atomicAdd(&cnt[dst[e]], 1);
}

__global__ void scan_part(const int* __restrict__ cnt, int* __restrict__ partials) {
    __shared__ int sm[256];
    int b = blockIdx.x, t = threadIdx.x;
    int i = b * 256 + t;
    sm[t] = (i < N_NODES) ? cnt[i] : 0;
    __syncthreads();
    for (int off = 128; off > 0; off >>= 1) {
        if (t < off) sm[t] += sm[t + off];
        __syncthreads();
    }
    if (t == 0) partials[b] = sm[0];
}

__global__ void scan_mid(const int* __restrict__ partials, int* __restrict__ offsets) {
    __shared__ int sm[256];
    int t = threadIdx.x;
    int v = (t < NPART) ? partials[t] : 0;
    sm[t] = v;
    __syncthreads();
    for (int off = 1; off < 256; off <<= 1) {
        int u = (t >= off) ? sm[t - off] : 0;
        __syncthreads();
        sm[t] += u;
        __syncthreads();
    }
    if (t < NPART) offsets[t] = sm[t] - v;   // exclusive prefix
}

__global__ void scan_final(const int* __restrict__ cnt, const int* __restrict__ offsets,
                           int* __restrict__ rowptr) {
    __shared__ int sm[256];
    int b = blockIdx.x, t = threadIdx.x;
    int i = b * 256 + t;
    int v = (i < N_NODES) ? cnt[i] : 0;
    sm[t] = v;
    __syncthreads();
    for (int off = 1; off < 256; off <<= 1) {
        int u = (t >= off) ? sm[t - off] : 0;
        __syncthreads();
        sm[t] += u;
        __syncthreads();
    }
    if (i < N_NODES) rowptr[i + 1] = sm[t] + offsets[b];
    if (i == 0) rowptr[0] = 0;
}

__global__ void fill_kernel(const int* __restrict__ src, const int* __restrict__ dst,
                            const int* __restrict__ rowptr, int* __restrict__ cursor,
                            int* __restrict__ col) {
    int e = blockIdx.x * blockDim.x + threadIdx.x;
    if (e < N_EDGES) {
        int d = dst[e];
        int pos = atomicAdd(&cursor[d], 1);
        col[rowptr[d] + pos] = src[e];
    }
}

// ---------------------------------------------------------------- aggregate
// one wave (64 lanes) per node, f32x2 per lane; deg_inv folded in

__global__ __launch_bounds__(256) void aggregate_kernel(
    const float* __restrict__ h, const int* __restrict__ rowptr,
    const int* __restrict__ col, const int* __restrict__ cnt,
    float* __restrict__ agg)
{
    int node = blockIdx.x * 4 + (threadIdx.x >> 6);
    int l = threadIdx.x & 63;
    if (node >= N_NODES) return;
    int beg = rowptr[node], end = rowptr[node + 1];
    f32x2 s = {0.f, 0.f};
    int e = beg;
    for (; e + 3 < end; e += 4) {
        int c0 = col[e], c1 = col[e + 1], c2 = col[e + 2], c3 = col[e + 3];
        f32x2 v0 = *(const f32x2*)&h[(size_t)c0 * 128 + l * 2];
        f32x2 v1 = *(const f32x2*)&h[(size_t)c1 * 128 + l * 2];
        f32x2 v2 = *(const f32x2*)&h[(size_t)c2 * 128 + l * 2];
        f32x2 v3 = *(const f32x2*)&h[(size_t)c3 * 128 + l * 2];
        s += (v0 + v1) + (v2 + v3);
    }
    for (; e < end; ++e)
        s += *(const f32x2*)&h[(size_t)col[e] * 128 + l * 2];
    float dinv = 1.0f / (float)max(cnt[node], 1);
    s *= dinv;
    *(f32x2*)&agg[(size_t)node * 128 + l * 2] = s;
}

// ---------------------------------------------------------------- weight prep
// Wt_hi/Wt_lo: [NOUT][256] bf16 (transposed + split); k<128 -> Wself, k>=128 -> Wneigh

template <int NOUT>
__global__ void wsplit_kernel(const float* __restrict__ Ws, const float* __restrict__ Wn,
                              short* __restrict__ Wt_hi, short* __restrict__ Wt_lo) {
    int idx = blockIdx.x * 256 + threadIdx.x;      // c*256 + k
    if (idx >= NOUT * 256) return;
    int c = idx >> 8, k = idx & 255;
    float v = (k < 128) ? Ws[(size_t)k * NOUT + c] : Wn[(size_t)(k - 128) * NOUT + c];
    short hi = f2bf(v);
    float lo = v - bf2f(hi);
    Wt_hi[idx] = hi;
    Wt_lo[idx] = f2bf(lo);
}

// ---------------------------------------------------------------- combine GEMM
// out[n,j] = relu([h|agg][n,:] @ Wcat[:,j] + b), K=256, split-bf16 (3 MFMA).
// 64x64 tile, 256 thr (4 waves, 16 rows each). T14: next k-tile's global
// loads issued to regs before current tile's convert+MFMA.

template <int NOUT, bool RELU>
__global__ __launch_bounds__(256) void combine_mfma(
    const float* __restrict__ h, const float* __restrict__ agg,
    const short* __restrict__ Wt_hi, const short* __restrict__ Wt_lo,
    const float* __restrict__ bias, float* __restrict__ out)
{
    __shared__ __attribute__((aligned(16))) short Ahi[64 * 64];
    __shared__ __attribute__((aligned(16))) short Alo[64 * 64];

    const int tid  = threadIdx.x;
    const int lane = tid & 63;
    const int wave = tid >> 6;
    const int bm = blockIdx.x, bn = blockIdx.y;
    const int row0 = bm * 64;
    const int rr = lane & 15;
    const int kg = lane >> 4;

    // staging chunks: cid = tid and tid+256; r = cid>>3 (0..63), c8 = cid&7
    const int r0c = tid >> 3;
    const int r1c = (tid + 256) >> 3;
    const int c8c = tid & 7;

    f32x4 acc[4];
    #pragma unroll
    for (int j = 0; j < 4; ++j) acc[j] = (f32x4){0.f, 0.f, 0.f, 0.f};

    float4 buf[2][2][2];   // [parity][chunk][half]

#define ISSUE(KT, P) do {                                                      \
        const float* srcb_ = ((KT) < 2) ? h : agg;                             \
        const int kb_ = ((KT) & 1) * 64;                                       \
        {   int grow_ = row0 + r0c;                                            \
            float4 v0_ = {0,0,0,0}, v1_ = {0,0,0,0};                           \
            if (grow_ < N_NODES) {                                             \
                const float* sp_ = srcb_ + (size_t)grow_ * 128 + kb_ + c8c * 8;\
                v0_ = *(const float4*)sp_; v1_ = *(const float4*)(sp_ + 4);    \
            }                                                                  \
            buf[P][0][0] = v0_; buf[P][0][1] = v1_; }                          \
        {   int grow_ = row0 + r1c;                                            \
            float4 v0_ = {0,0,0,0}, v1_ = {0,0,0,0};                           \
            if (grow_ < N_NODES) {                                             \
                const float* sp_ = srcb_ + (size_t)grow_ * 128 + kb_ + c8c * 8;\
                v0_ = *(const float4*)sp_; v1_ = *(const float4*)(sp_ + 4);    \
            }                                                                  \
            buf[P][1][0] = v0_; buf[P][1][1] = v1_; }                          \
    } while (0)

    ISSUE(0, 0);

    #pragma unroll
    for (int kt = 0; kt < 4; ++kt) {
        const int p = kt & 1, q = p ^ 1;
        if (kt < 3) {
            if (kt + 1 == 1) ISSUE(1, 1);
            else if (kt + 1 == 2) ISSUE(2, 0 ^ 0 ? 0 : (q)); // q static per kt
            else ISSUE(3, q);
        }
        // NOTE: the branches above are all compile-time (kt unrolled);
        // ISSUE(kt+1, q) semantics.
        // ---- convert buf[p] -> swizzled LDS
        #pragma unroll
        for (int c = 0; c < 2; ++c) {
            int r = (c == 0) ? r0c : r1c;
            float vv[8] = { buf[p][c][0].x, buf[p][c][0].y, buf[p][c][0].z, buf[p][c][0].w,
                            buf[p][c][1].x, buf[p][c][1].y, buf[p][c][1].z, buf[p][c][1].w };
            bf16x8 hv, lv;
            #pragma unroll
            for (int e = 0; e < 8; ++e) {
                short hb = f2bf(vv[e]);
                hv[e] = hb;
                lv[e] = f2bf(vv[e] - bf2f(hb));
            }
            int a16 = r * 8 + (c8c ^ (r & 7));
            ((bf16x8*)Ahi)[a16] = hv;
            ((bf16x8*)Alo)[a16] = lv;
        }
        __syncthreads();

        // ---- compute: 2 MFMA k-steps of 32
        #pragma unroll
        for (int ks = 0; ks < 2; ++ks) {
            int row = wave * 16 + rr;
            int kc = ks * 4 + kg;
            int a16 = row * 8 + (kc ^ (row & 7));
            bf16x8 ah = ((const bf16x8*)Ahi)[a16];
            bf16x8 al = ((const bf16x8*)Alo)[a16];
            int kglob = kt * 64 + ks * 32 + kg * 8;
            #pragma unroll
            for (int nj = 0; nj < 4; ++nj) {
                int colg = bn * 64 + nj * 16 + rr;
                bf16x8 bh = *(const bf16x8*)(Wt_hi + (size_t)colg * 256 + kglob);
                bf16x8 bl = *(const bf16x8*)(Wt_lo + (size_t)colg * 256 + kglob);
                acc[nj] = __builtin_amdgcn_mfma_f32_16x16x32_bf16(ah, bh, acc[nj], 0, 0, 0);
                acc[nj] = __builtin_amdgcn_mfma_f32_16x16x32_bf16(al, bh, acc[nj], 0, 0, 0);
                acc[nj] = __builtin_amdgcn_mfma_f32_16x16x32_bf16(ah, bl, acc[nj], 0, 0, 0);
            }
        }
        __syncthreads();
    }
#undef ISSUE

    // ---- epilogue: D col=lane&15, row=(lane>>4)*4+r
    const int rg = lane >> 4;
    #pragma unroll
    for (int nj = 0; nj < 4; ++nj) {
        int colg = bn * 64 + nj * 16 + rr;
        float bv = bias[colg];
        #pragma unroll
        for (int r = 0; r < 4; ++r) {
            int row = row0 + wave * 16 + rg * 4 + r;
            if (row < N_NODES) {
                float v = acc[nj][r] + bv;
                if (RELU) v = fmaxf(v, 0.f);
                out[(size_t)row * NOUT + colg] = v;
            }
        }
    }
}

// ---------------------------------------------------------------- launch

extern "C" void kernel_launch(void* const* d_in, const int* in_sizes, int n_in,
                              void* d_out, int out_size, void* d_ws, size_t ws_size,
                              hipStream_t stream) {
    const float* x   = (const float*)d_in[0];
    const int*   src = (const int*)d_in[1];
    const int*   dst = (const int*)d_in[2];
    const float* Ws0 = (const float*)d_in[3];
    const float* Wn0 = (const float*)d_in[4];
    const float* b0  = (const float*)d_in[5];
    const float* Ws1 = (const float*)d_in[6];
    const float* Wn1 = (const float*)d_in[7];
    const float* b1  = (const float*)d_in[8];
    const float* Ws2 = (const float*)d_in[9];
    const float* Wn2 = (const float*)d_in[10];
    const float* b2  = (const float*)d_in[11];
    float* out = (float*)d_out;

    char* p = (char*)d_ws;
    auto alloc = [&](size_t bytes) {
        char* r = p;
        p += (bytes + 255) & ~(size_t)255;
        return r;
    };
    int*   cnt      = (int*)alloc((size_t)N_NODES * 4);
    int*   cursor   = (int*)alloc((size_t)N_NODES * 4);
    int*   rowptr   = (int*)alloc((size_t)(N_NODES + 1) * 4);
    int*   col      = (int*)alloc((size_t)N_EDGES * 4);
    int*   partials = (int*)alloc((size_t)NPART * 4);
    int*   offsets  = (int*)alloc((size_t)NPART * 4);
    float* agg      = (float*)alloc((size_t)N_NODES * 128 * 4);
    float* hA       = (float*)alloc((size_t)N_NODES * 128 * 4);
    float* hB       = (float*)alloc((size_t)N_NODES * 128 * 4);
    short* Wt0_hi   = (short*)alloc((size_t)128 * 256 * 2);
    short* Wt0_lo   = (short*)alloc((size_t)128 * 256 * 2);
    short* Wt1_hi   = (short*)alloc((size_t)128 * 256 * 2);
    short* Wt1_lo   = (short*)alloc((size_t)128 * 256 * 2);
    short* Wt2_hi   = (short*)alloc((size_t)64 * 256 * 2);
    short* Wt2_lo   = (short*)alloc((size_t)64 * 256 * 2);

    hipMemsetAsync(cnt, 0, (size_t)N_NODES * 4, stream);
    hipMemsetAsync(cursor, 0, (size_t)N_NODES * 4, stream);

    // CSR build
    count_kernel<<<(N_EDGES + 255) / 256, 256, 0, stream>>>(dst, cnt);
    scan_part <<<NPART, 256, 0, stream>>>(cnt, partials);
    scan_mid  <<<1, 256, 0, stream>>>(partials, offsets);
    scan_final<<<NPART, 256, 0, stream>>>(cnt, offsets, rowptr);
    fill_kernel<<<(N_EDGES + 255) / 256, 256, 0, stream>>>(src, dst, rowptr, cursor, col);

    // weight prep (transpose + hi/lo split)
    wsplit_kernel<128><<<(128 * 256 + 255) / 256, 256, 0, stream>>>(Ws0, Wn0, Wt0_hi, Wt0_lo);
    wsplit_kernel<128><<<(128 * 256 + 255) / 256, 256, 0, stream>>>(Ws1, Wn1, Wt1_hi, Wt1_lo);
    wsplit_kernel<64> <<<(64 * 256 + 255) / 256, 256, 0, stream>>>(Ws2, Wn2, Wt2_hi, Wt2_lo);

    const int AGB = (N_NODES + 3) / 4;        // 12500
    const int MB  = (N_NODES + 63) / 64;      // 782
    dim3 g01(MB, 2), g2(MB, 1);

    // layer 0
    aggregate_kernel<<<AGB, 256, 0, stream>>>(x, rowptr, col, cnt, agg);
    combine_mfma<128, true><<<g01, 256, 0, stream>>>(x, agg, Wt0_hi, Wt0_lo, b0, hA);
    // layer 1
    aggregate_kernel<<<AGB, 256, 0, stream>>>(hA, rowptr, col, cnt, agg);
    combine_mfma<128, true><<<g01, 256, 0, stream>>>(hA, agg, Wt1_hi, Wt1_lo, b1, hB);
    // layer 2
    aggregate_kernel<<<AGB, 256, 0, stream>>>(hB, rowptr, col, cnt, agg);
    combine_mfma<64, false><<<g2, 256, 0, stream>>>(hB, agg, Wt2_hi, Wt2_lo, b2, out);
}

// Round 4
// 322.805 us; speedup vs baseline: 1.1897x; 1.1897x over previous
//
#include <hip/hip_runtime.h>

#define N_NODES 50000
#define N_EDGES 600000
#define NPART 196   // ceil(50000/256)

using f32x2  = __attribute__((ext_vector_type(2))) float;
using f32x4  = __attribute__((ext_vector_type(4))) float;
using bf16x8 = __attribute__((ext_vector_type(8))) short;

__device__ inline short f2bf(float f) {
    uint32_t u = __builtin_bit_cast(uint32_t, f);
    uint32_t r = (u + 0x7FFFu + ((u >> 16) & 1u)) >> 16;
    return (short)r;
}
__device__ inline float bf2f(short h) {
    uint32_t u = ((uint32_t)(uint16_t)h) << 16;
    return __builtin_bit_cast(float, u);
}

// ---------------------------------------------------------------- CSR build

__global__ void count_kernel(const int* __restrict__ dst, int* __restrict__ cnt) {
    int e = blockIdx.x * blockDim.x + threadIdx.x;
    if (e < N_EDGES) atomicAdd(&cnt[dst[e]], 1);
}

__global__ void scan_part(const int* __restrict__ cnt, int* __restrict__ partials) {
    __shared__ int sm[256];
    int b = blockIdx.x, t = threadIdx.x;
    int i = b * 256 + t;
    sm[t] = (i < N_NODES) ? cnt[i] : 0;
    __syncthreads();
    for (int off = 128; off > 0; off >>= 1) {
        if (t < off) sm[t] += sm[t + off];
        __syncthreads();
    }
    if (t == 0) partials[b] = sm[0];
}

__global__ void scan_mid(const int* __restrict__ partials, int* __restrict__ offsets) {
    __shared__ int sm[256];
    int t = threadIdx.x;
    int v = (t < NPART) ? partials[t] : 0;
    sm[t] = v;
    __syncthreads();
    for (int off = 1; off < 256; off <<= 1) {
        int u = (t >= off) ? sm[t - off] : 0;
        __syncthreads();
        sm[t] += u;
        __syncthreads();
    }
    if (t < NPART) offsets[t] = sm[t] - v;   // exclusive prefix
}

__global__ void scan_final(const int* __restrict__ cnt, const int* __restrict__ offsets,
                           int* __restrict__ rowptr) {
    __shared__ int sm[256];
    int b = blockIdx.x, t = threadIdx.x;
    int i = b * 256 + t;
    int v = (i < N_NODES) ? cnt[i] : 0;
    sm[t] = v;
    __syncthreads();
    for (int off = 1; off < 256; off <<= 1) {
        int u = (t >= off) ? sm[t - off] : 0;
        __syncthreads();
        sm[t] += u;
        __syncthreads();
    }
    if (i < N_NODES) rowptr[i + 1] = sm[t] + offsets[b];
    if (i == 0) rowptr[0] = 0;
}

__global__ void fill_kernel(const int* __restrict__ src, const int* __restrict__ dst,
                            const int* __restrict__ rowptr, int* __restrict__ cursor,
                            int* __restrict__ col) {
    int e = blockIdx.x * blockDim.x + threadIdx.x;
    if (e < N_EDGES) {
        int d = dst[e];
        int pos = atomicAdd(&cursor[d], 1);
        col[rowptr[d] + pos] = src[e];
    }
}

// ---------------------------------------------------------------- aggregate
// one wave (64 lanes) per node, f32x2 per lane; deg_inv folded in

__global__ __launch_bounds__(256) void aggregate_kernel(
    const float* __restrict__ h, const int* __restrict__ rowptr,
    const int* __restrict__ col, const int* __restrict__ cnt,
    float* __restrict__ agg)
{
    int node = blockIdx.x * 4 + (threadIdx.x >> 6);
    int l = threadIdx.x & 63;
    if (node >= N_NODES) return;
    int beg = rowptr[node], end = rowptr[node + 1];
    f32x2 s = {0.f, 0.f};
    int e = beg;
    for (; e + 3 < end; e += 4) {
        int c0 = col[e], c1 = col[e + 1], c2 = col[e + 2], c3 = col[e + 3];
        f32x2 v0 = *(const f32x2*)&h[(size_t)c0 * 128 + l * 2];
        f32x2 v1 = *(const f32x2*)&h[(size_t)c1 * 128 + l * 2];
        f32x2 v2 = *(const f32x2*)&h[(size_t)c2 * 128 + l * 2];
        f32x2 v3 = *(const f32x2*)&h[(size_t)c3 * 128 + l * 2];
        s += (v0 + v1) + (v2 + v3);
    }
    for (; e < end; ++e)
        s += *(const f32x2*)&h[(size_t)col[e] * 128 + l * 2];
    float dinv = 1.0f / (float)max(cnt[node], 1);
    s *= dinv;
    *(f32x2*)&agg[(size_t)node * 128 + l * 2] = s;
}

// ---------------------------------------------------------------- weight prep
// Wt_hi/Wt_lo: [NOUT][256] bf16 (transposed + split); k<128 -> Wself, k>=128 -> Wneigh

template <int NOUT>
__global__ void wsplit_kernel(const float* __restrict__ Ws, const float* __restrict__ Wn,
                              short* __restrict__ Wt_hi, short* __restrict__ Wt_lo) {
    int idx = blockIdx.x * 256 + threadIdx.x;      // c*256 + k
    if (idx >= NOUT * 256) return;
    int c = idx >> 8, k = idx & 255;
    float v = (k < 128) ? Ws[(size_t)k * NOUT + c] : Wn[(size_t)(k - 128) * NOUT + c];
    short hi = f2bf(v);
    float lo = v - bf2f(hi);
    Wt_hi[idx] = hi;
    Wt_lo[idx] = f2bf(lo);
}

// ---------------------------------------------------------------- combine GEMM v2
// out[n,j] = relu([h|agg][n,:] @ Wcat[:,j] + b), K=256, split-bf16 (3 MFMA).
// Tile 128 rows x 32 cols, 4 waves (wave owns 32 rows = 2 m-frags).
// B (hi+lo) staged in LDS ONCE (pitch-33 16B chunks, bank-spread);
// A read per-fragment direct from global, converted in-reg. ZERO barriers
// in the k-loop -> waves free-run, latency hidden by ILP.

template <int NOUT, bool RELU>
__global__ __launch_bounds__(256) void combine_mfma2(
    const float* __restrict__ h, const float* __restrict__ agg,
    const short* __restrict__ Wth, const short* __restrict__ Wtl,
    const float* __restrict__ bias, float* __restrict__ out)
{
    __shared__ __attribute__((aligned(16))) short Bh[32 * 33 * 8];
    __shared__ __attribute__((aligned(16))) short Bl[32 * 33 * 8];

    const int tid  = threadIdx.x;
    const int lane = tid & 63;
    const int wave = tid >> 6;
    const int colbase = blockIdx.x * 32;   // bn fastest -> consecutive blocks share A rows
    const int row0    = blockIdx.y * 128;
    const int rr = lane & 15;
    const int kq = lane >> 4;              // 0..3

    // ---- stage B once: thread -> col (0..31), 4 chunks of 8 shorts
    {
        int col = tid >> 3;
        int kc0 = (tid & 7) * 4;
        const short* gh = Wth + (size_t)(colbase + col) * 256 + kc0 * 8;
        const short* gl = Wtl + (size_t)(colbase + col) * 256 + kc0 * 8;
        #pragma unroll
        for (int j = 0; j < 4; ++j) {
            ((bf16x8*)Bh)[col * 33 + kc0 + j] = *(const bf16x8*)(gh + j * 8);
            ((bf16x8*)Bl)[col * 33 + kc0 + j] = *(const bf16x8*)(gl + j * 8);
        }
    }
    __syncthreads();

    f32x4 acc[2][2];
    #pragma unroll
    for (int i = 0; i < 2; ++i)
        #pragma unroll
        for (int j = 0; j < 2; ++j)
            acc[i][j] = (f32x4){0.f, 0.f, 0.f, 0.f};

    #pragma unroll
    for (int ks = 0; ks < 8; ++ks) {
        const float* base = (ks < 4) ? h : agg;
        const int kf = (ks & 3) * 32 + kq * 8;   // f32 offset within row

        bf16x8 ah[2], al[2];
        #pragma unroll
        for (int mi = 0; mi < 2; ++mi) {
            int row = row0 + wave * 32 + mi * 16 + rr;
            f32x4 v0 = {0.f, 0.f, 0.f, 0.f}, v1 = {0.f, 0.f, 0.f, 0.f};
            if (row < N_NODES) {
                const float* sp = base + (size_t)row * 128 + kf;
                v0 = *(const f32x4*)sp;
                v1 = *(const f32x4*)(sp + 4);
            }
            float vv[8] = {v0[0], v0[1], v0[2], v0[3], v1[0], v1[1], v1[2], v1[3]};
            #pragma unroll
            for (int e = 0; e < 8; ++e) {
                short hb = f2bf(vv[e]);
                ah[mi][e] = hb;
                al[mi][e] = f2bf(vv[e] - bf2f(hb));
            }
        }

        #pragma unroll
        for (int nj = 0; nj < 2; ++nj) {
            int colL = nj * 16 + rr;
            int kc = ks * 4 + kq;
            bf16x8 bh = ((const bf16x8*)Bh)[colL * 33 + kc];
            bf16x8 bl = ((const bf16x8*)Bl)[colL * 33 + kc];
            #pragma unroll
            for (int mi = 0; mi < 2; ++mi) {
                acc[mi][nj] = __builtin_amdgcn_mfma_f32_16x16x32_bf16(ah[mi], bh, acc[mi][nj], 0, 0, 0);
                acc[mi][nj] = __builtin_amdgcn_mfma_f32_16x16x32_bf16(al[mi], bh, acc[mi][nj], 0, 0, 0);
                acc[mi][nj] = __builtin_amdgcn_mfma_f32_16x16x32_bf16(ah[mi], bl, acc[mi][nj], 0, 0, 0);
            }
        }
    }

    // ---- epilogue: D col=lane&15, row=(lane>>4)*4+r
    const int rg = lane >> 4;
    #pragma unroll
    for (int nj = 0; nj < 2; ++nj) {
        int colg = colbase + nj * 16 + rr;
        float bv = bias[colg];
        #pragma unroll
        for (int mi = 0; mi < 2; ++mi) {
            #pragma unroll
            for (int r = 0; r < 4; ++r) {
                int row = row0 + wave * 32 + mi * 16 + rg * 4 + r;
                if (row < N_NODES) {
                    float v = acc[mi][nj][r] + bv;
                    if (RELU) v = fmaxf(v, 0.f);
                    out[(size_t)row * NOUT + colg] = v;
                }
            }
        }
    }
}

// ---------------------------------------------------------------- launch

extern "C" void kernel_launch(void* const* d_in, const int* in_sizes, int n_in,
                              void* d_out, int out_size, void* d_ws, size_t ws_size,
                              hipStream_t stream) {
    const float* x   = (const float*)d_in[0];
    const int*   src = (const int*)d_in[1];
    const int*   dst = (const int*)d_in[2];
    const float* Ws0 = (const float*)d_in[3];
    const float* Wn0 = (const float*)d_in[4];
    const float* b0  = (const float*)d_in[5];
    const float* Ws1 = (const float*)d_in[6];
    const float* Wn1 = (const float*)d_in[7];
    const float* b1  = (const float*)d_in[8];
    const float* Ws2 = (const float*)d_in[9];
    const float* Wn2 = (const float*)d_in[10];
    const float* b2  = (const float*)d_in[11];
    float* out = (float*)d_out;

    char* p = (char*)d_ws;
    auto alloc = [&](size_t bytes) {
        char* r = p;
        p += (bytes + 255) & ~(size_t)255;
        return r;
    };
    int*   cnt      = (int*)alloc((size_t)N_NODES * 4);
    int*   cursor   = (int*)alloc((size_t)N_NODES * 4);
    int*   rowptr   = (int*)alloc((size_t)(N_NODES + 1) * 4);
    int*   col      = (int*)alloc((size_t)N_EDGES * 4);
    int*   partials = (int*)alloc((size_t)NPART * 4);
    int*   offsets  = (int*)alloc((size_t)NPART * 4);
    float* agg      = (float*)alloc((size_t)N_NODES * 128 * 4);
    float* hA       = (float*)alloc((size_t)N_NODES * 128 * 4);
    float* hB       = (float*)alloc((size_t)N_NODES * 128 * 4);
    short* Wt0_hi   = (short*)alloc((size_t)128 * 256 * 2);
    short* Wt0_lo   = (short*)alloc((size_t)128 * 256 * 2);
    short* Wt1_hi   = (short*)alloc((size_t)128 * 256 * 2);
    short* Wt1_lo   = (short*)alloc((size_t)128 * 256 * 2);
    short* Wt2_hi   = (short*)alloc((size_t)64 * 256 * 2);
    short* Wt2_lo   = (short*)alloc((size_t)64 * 256 * 2);

    hipMemsetAsync(cnt, 0, (size_t)N_NODES * 4, stream);
    hipMemsetAsync(cursor, 0, (size_t)N_NODES * 4, stream);

    // CSR build
    count_kernel<<<(N_EDGES + 255) / 256, 256, 0, stream>>>(dst, cnt);
    scan_part <<<NPART, 256, 0, stream>>>(cnt, partials);
    scan_mid  <<<1, 256, 0, stream>>>(partials, offsets);
    scan_final<<<NPART, 256, 0, stream>>>(cnt, offsets, rowptr);
    fill_kernel<<<(N_EDGES + 255) / 256, 256, 0, stream>>>(src, dst, rowptr, cursor, col);

    // weight prep (transpose + hi/lo split)
    wsplit_kernel<128><<<(128 * 256 + 255) / 256, 256, 0, stream>>>(Ws0, Wn0, Wt0_hi, Wt0_lo);
    wsplit_kernel<128><<<(128 * 256 + 255) / 256, 256, 0, stream>>>(Ws1, Wn1, Wt1_hi, Wt1_lo);
    wsplit_kernel<64> <<<(64 * 256 + 255) / 256, 256, 0, stream>>>(Ws2, Wn2, Wt2_hi, Wt2_lo);

    const int AGB = (N_NODES + 3) / 4;        // 12500
    const int MB  = (N_NODES + 127) / 128;    // 391
    dim3 g01(4, MB), g2(2, MB);               // x = col-block (fast), y = row-block

    // layer 0
    aggregate_kernel<<<AGB, 256, 0, stream>>>(x, rowptr, col, cnt, agg);
    combine_mfma2<128, true><<<g01, 256, 0, stream>>>(x, agg, Wt0_hi, Wt0_lo, b0, hA);
    // layer 1
    aggregate_kernel<<<AGB, 256, 0, stream>>>(hA, rowptr, col, cnt, agg);
    combine_mfma2<128, true><<<g01, 256, 0, stream>>>(hA, agg, Wt1_hi, Wt1_lo, b1, hB);
    // layer 2
    aggregate_kernel<<<AGB, 256, 0, stream>>>(hB, rowptr, col, cnt, agg);
    combine_mfma2<64, false><<<g2, 256, 0, stream>>>(hB, agg, Wt2_hi, Wt2_lo, b2, out);
}

// Round 5
// 300.368 us; speedup vs baseline: 1.2786x; 1.0747x over previous
//
#include <hip/hip_runtime.h>

#define N_NODES 50000
#define N_EDGES 600000
#define NPART 196   // ceil(50000/256)

using f32x2  = __attribute__((ext_vector_type(2))) float;
using f32x4  = __attribute__((ext_vector_type(4))) float;
using bf16x8 = __attribute__((ext_vector_type(8))) short;

__device__ inline short f2bf(float f) {
    uint32_t u = __builtin_bit_cast(uint32_t, f);
    uint32_t r = (u + 0x7FFFu + ((u >> 16) & 1u)) >> 16;
    return (short)r;
}
__device__ inline float bf2f(short h) {
    uint32_t u = ((uint32_t)(uint16_t)h) << 16;
    return __builtin_bit_cast(float, u);
}

// ---------------------------------------------------------------- CSR build

__global__ void count_kernel(const int* __restrict__ dst, int* __restrict__ cnt) {
    int e = blockIdx.x * blockDim.x + threadIdx.x;
    if (e < N_EDGES) atomicAdd(&cnt[dst[e]], 1);
}

__global__ void scan_part(const int* __restrict__ cnt, int* __restrict__ partials) {
    __shared__ int sm[256];
    int b = blockIdx.x, t = threadIdx.x;
    int i = b * 256 + t;
    sm[t] = (i < N_NODES) ? cnt[i] : 0;
    __syncthreads();
    for (int off = 128; off > 0; off >>= 1) {
        if (t < off) sm[t] += sm[t + off];
        __syncthreads();
    }
    if (t == 0) partials[b] = sm[0];
}

__global__ void scan_mid(const int* __restrict__ partials, int* __restrict__ offsets) {
    __shared__ int sm[256];
    int t = threadIdx.x;
    int v = (t < NPART) ? partials[t] : 0;
    sm[t] = v;
    __syncthreads();
    for (int off = 1; off < 256; off <<= 1) {
        int u = (t >= off) ? sm[t - off] : 0;
        __syncthreads();
        sm[t] += u;
        __syncthreads();
    }
    if (t < NPART) offsets[t] = sm[t] - v;   // exclusive prefix
}

__global__ void scan_final(const int* __restrict__ cnt, const int* __restrict__ offsets,
                           int* __restrict__ rowptr) {
    __shared__ int sm[256];
    int b = blockIdx.x, t = threadIdx.x;
    int i = b * 256 + t;
    int v = (i < N_NODES) ? cnt[i] : 0;
    sm[t] = v;
    __syncthreads();
    for (int off = 1; off < 256; off <<= 1) {
        int u = (t >= off) ? sm[t - off] : 0;
        __syncthreads();
        sm[t] += u;
        __syncthreads();
    }
    if (i < N_NODES) rowptr[i + 1] = sm[t] + offsets[b];
    if (i == 0) rowptr[0] = 0;
}

__global__ void fill_kernel(const int* __restrict__ src, const int* __restrict__ dst,
                            const int* __restrict__ rowptr, int* __restrict__ cursor,
                            int* __restrict__ col) {
    int e = blockIdx.x * blockDim.x + threadIdx.x;
    if (e < N_EDGES) {
        int d = dst[e];
        int pos = atomicAdd(&cursor[d], 1);
        col[rowptr[d] + pos] = src[e];
    }
}

// ---------------------------------------------------------------- bf16 cast (x -> xb)

__global__ void cast_bf16_kernel(const float* __restrict__ in, ushort* __restrict__ out) {
    int i = blockIdx.x * 256 + threadIdx.x;      // 4 floats per thread
    if (i >= N_NODES * 32) return;
    f32x4 v = *(const f32x4*)(in + (size_t)i * 4);
    ushort4 o;
    o.x = (ushort)f2bf(v[0]); o.y = (ushort)f2bf(v[1]);
    o.z = (ushort)f2bf(v[2]); o.w = (ushort)f2bf(v[3]);
    *(ushort4*)(out + (size_t)i * 4) = o;
}

// ---------------------------------------------------------------- aggregate (bf16 gather)
// one wave per node; lane loads 1 dword = 2 bf16; f32 accumulate; deg_inv folded

__global__ __launch_bounds__(256) void aggregate_kernel(
    const ushort* __restrict__ hb, const int* __restrict__ rowptr,
    const int* __restrict__ col, const int* __restrict__ cnt,
    float* __restrict__ agg)
{
    int node = blockIdx.x * 4 + (threadIdx.x >> 6);
    int l = threadIdx.x & 63;
    if (node >= N_NODES) return;
    int beg = rowptr[node], end = rowptr[node + 1];
    float sx = 0.f, sy = 0.f;
    int e = beg;
    for (; e + 3 < end; e += 4) {
        int c0 = col[e], c1 = col[e + 1], c2 = col[e + 2], c3 = col[e + 3];
        uint32_t u0 = *(const uint32_t*)&hb[(size_t)c0 * 128 + l * 2];
        uint32_t u1 = *(const uint32_t*)&hb[(size_t)c1 * 128 + l * 2];
        uint32_t u2 = *(const uint32_t*)&hb[(size_t)c2 * 128 + l * 2];
        uint32_t u3 = *(const uint32_t*)&hb[(size_t)c3 * 128 + l * 2];
        sx += __builtin_bit_cast(float, u0 << 16) + __builtin_bit_cast(float, u1 << 16)
            + __builtin_bit_cast(float, u2 << 16) + __builtin_bit_cast(float, u3 << 16);
        sy += __builtin_bit_cast(float, u0 & 0xffff0000u) + __builtin_bit_cast(float, u1 & 0xffff0000u)
            + __builtin_bit_cast(float, u2 & 0xffff0000u) + __builtin_bit_cast(float, u3 & 0xffff0000u);
    }
    for (; e < end; ++e) {
        uint32_t u = *(const uint32_t*)&hb[(size_t)col[e] * 128 + l * 2];
        sx += __builtin_bit_cast(float, u << 16);
        sy += __builtin_bit_cast(float, u & 0xffff0000u);
    }
    float dinv = 1.0f / (float)max(cnt[node], 1);
    f32x2 s = {sx * dinv, sy * dinv};
    *(f32x2*)&agg[(size_t)node * 128 + l * 2] = s;
}

// ---------------------------------------------------------------- weight prep
// Wt_hi/Wt_lo: [NOUT][256] bf16 (transposed + split); k<128 -> Wself, k>=128 -> Wneigh

template <int NOUT>
__global__ void wsplit_kernel(const float* __restrict__ Ws, const float* __restrict__ Wn,
                              short* __restrict__ Wt_hi, short* __restrict__ Wt_lo) {
    int idx = blockIdx.x * 256 + threadIdx.x;      // c*256 + k
    if (idx >= NOUT * 256) return;
    int c = idx >> 8, k = idx & 255;
    float v = (k < 128) ? Ws[(size_t)k * NOUT + c] : Wn[(size_t)(k - 128) * NOUT + c];
    short hi = f2bf(v);
    float lo = v - bf2f(hi);
    Wt_hi[idx] = hi;
    Wt_lo[idx] = f2bf(lo);
}

// ---------------------------------------------------------------- combine GEMM v2
// out[n,j] = relu([h|agg][n,:] @ Wcat[:,j] + b), K=256, split-bf16 (3 MFMA).
// Tile 128 rows x 32 cols, 4 waves. B staged in LDS once (pitch-33 chunks);
// A direct from global per fragment, converted in-reg; zero k-loop barriers.
// Optionally dual-writes bf16 copy of output for the next layer's gather.

template <int NOUT, bool RELU, bool WRITE_BF16>
__global__ __launch_bounds__(256) void combine_mfma2(
    const float* __restrict__ h, const float* __restrict__ agg,
    const short* __restrict__ Wth, const short* __restrict__ Wtl,
    const float* __restrict__ bias, float* __restrict__ out,
    ushort* __restrict__ out_bf16)
{
    __shared__ __attribute__((aligned(16))) short Bh[32 * 33 * 8];
    __shared__ __attribute__((aligned(16))) short Bl[32 * 33 * 8];

    const int tid  = threadIdx.x;
    const int lane = tid & 63;
    const int wave = tid >> 6;
    const int colbase = blockIdx.x * 32;
    const int row0    = blockIdx.y * 128;
    const int rr = lane & 15;
    const int kq = lane >> 4;              // 0..3

    // ---- stage B once
    {
        int col = tid >> 3;
        int kc0 = (tid & 7) * 4;
        const short* gh = Wth + (size_t)(colbase + col) * 256 + kc0 * 8;
        const short* gl = Wtl + (size_t)(colbase + col) * 256 + kc0 * 8;
        #pragma unroll
        for (int j = 0; j < 4; ++j) {
            ((bf16x8*)Bh)[col * 33 + kc0 + j] = *(const bf16x8*)(gh + j * 8);
            ((bf16x8*)Bl)[col * 33 + kc0 + j] = *(const bf16x8*)(gl + j * 8);
        }
    }
    __syncthreads();

    f32x4 acc[2][2];
    #pragma unroll
    for (int i = 0; i < 2; ++i)
        #pragma unroll
        for (int j = 0; j < 2; ++j)
            acc[i][j] = (f32x4){0.f, 0.f, 0.f, 0.f};

    #pragma unroll
    for (int ks = 0; ks < 8; ++ks) {
        const float* base = (ks < 4) ? h : agg;
        const int kf = (ks & 3) * 32 + kq * 8;

        bf16x8 ah[2], al[2];
        #pragma unroll
        for (int mi = 0; mi < 2; ++mi) {
            int row = row0 + wave * 32 + mi * 16 + rr;
            f32x4 v0 = {0.f, 0.f, 0.f, 0.f}, v1 = {0.f, 0.f, 0.f, 0.f};
            if (row < N_NODES) {
                const float* sp = base + (size_t)row * 128 + kf;
                v0 = *(const f32x4*)sp;
                v1 = *(const f32x4*)(sp + 4);
            }
            float vv[8] = {v0[0], v0[1], v0[2], v0[3], v1[0], v1[1], v1[2], v1[3]};
            #pragma unroll
            for (int e = 0; e < 8; ++e) {
                short hb = f2bf(vv[e]);
                ah[mi][e] = hb;
                al[mi][e] = f2bf(vv[e] - bf2f(hb));
            }
        }

        #pragma unroll
        for (int nj = 0; nj < 2; ++nj) {
            int colL = nj * 16 + rr;
            int kc = ks * 4 + kq;
            bf16x8 bh = ((const bf16x8*)Bh)[colL * 33 + kc];
            bf16x8 bl = ((const bf16x8*)Bl)[colL * 33 + kc];
            #pragma unroll
            for (int mi = 0; mi < 2; ++mi) {
                acc[mi][nj] = __builtin_amdgcn_mfma_f32_16x16x32_bf16(ah[mi], bh, acc[mi][nj], 0, 0, 0);
                acc[mi][nj] = __builtin_amdgcn_mfma_f32_16x16x32_bf16(al[mi], bh, acc[mi][nj], 0, 0, 0);
                acc[mi][nj] = __builtin_amdgcn_mfma_f32_16x16x32_bf16(ah[mi], bl, acc[mi][nj], 0, 0, 0);
            }
        }
    }

    // ---- epilogue: D col=lane&15, row=(lane>>4)*4+r
    const int rg = lane >> 4;
    #pragma unroll
    for (int nj = 0; nj < 2; ++nj) {
        int colg = colbase + nj * 16 + rr;
        float bv = bias[colg];
        #pragma unroll
        for (int mi = 0; mi < 2; ++mi) {
            #pragma unroll
            for (int r = 0; r < 4; ++r) {
                int row = row0 + wave * 32 + mi * 16 + rg * 4 + r;
                if (row < N_NODES) {
                    float v = acc[mi][nj][r] + bv;
                    if (RELU) v = fmaxf(v, 0.f);
                    out[(size_t)row * NOUT + colg] = v;
                    if (WRITE_BF16)
                        out_bf16[(size_t)row * NOUT + colg] = (ushort)f2bf(v);
                }
            }
        }
    }
}

// ---------------------------------------------------------------- launch

extern "C" void kernel_launch(void* const* d_in, const int* in_sizes, int n_in,
                              void* d_out, int out_size, void* d_ws, size_t ws_size,
                              hipStream_t stream) {
    const float* x   = (const float*)d_in[0];
    const int*   src = (const int*)d_in[1];
    const int*   dst = (const int*)d_in[2];
    const float* Ws0 = (const float*)d_in[3];
    const float* Wn0 = (const float*)d_in[4];
    const float* b0  = (const float*)d_in[5];
    const float* Ws1 = (const float*)d_in[6];
    const float* Wn1 = (const float*)d_in[7];
    const float* b1  = (const float*)d_in[8];
    const float* Ws2 = (const float*)d_in[9];
    const float* Wn2 = (const float*)d_in[10];
    const float* b2  = (const float*)d_in[11];
    float* out = (float*)d_out;

    char* p = (char*)d_ws;
    auto alloc = [&](size_t bytes) {
        char* r = p;
        p += (bytes + 255) & ~(size_t)255;
        return r;
    };
    int*    cnt      = (int*)alloc((size_t)N_NODES * 4);
    int*    cursor   = (int*)alloc((size_t)N_NODES * 4);
    int*    rowptr   = (int*)alloc((size_t)(N_NODES + 1) * 4);
    int*    col      = (int*)alloc((size_t)N_EDGES * 4);
    int*    partials = (int*)alloc((size_t)NPART * 4);
    int*    offsets  = (int*)alloc((size_t)NPART * 4);
    float*  agg      = (float*)alloc((size_t)N_NODES * 128 * 4);
    float*  hA       = (float*)alloc((size_t)N_NODES * 128 * 4);
    float*  hB       = (float*)alloc((size_t)N_NODES * 128 * 4);
    ushort* nb       = (ushort*)alloc((size_t)N_NODES * 128 * 2);  // shared bf16 node buf
    short*  Wt0_hi   = (short*)alloc((size_t)128 * 256 * 2);
    short*  Wt0_lo   = (short*)alloc((size_t)128 * 256 * 2);
    short*  Wt1_hi   = (short*)alloc((size_t)128 * 256 * 2);
    short*  Wt1_lo   = (short*)alloc((size_t)128 * 256 * 2);
    short*  Wt2_hi   = (short*)alloc((size_t)64 * 256 * 2);
    short*  Wt2_lo   = (short*)alloc((size_t)64 * 256 * 2);

    hipMemsetAsync(cnt, 0, (size_t)N_NODES * 4, stream);
    hipMemsetAsync(cursor, 0, (size_t)N_NODES * 4, stream);

    // CSR build
    count_kernel<<<(N_EDGES + 255) / 256, 256, 0, stream>>>(dst, cnt);
    scan_part <<<NPART, 256, 0, stream>>>(cnt, partials);
    scan_mid  <<<1, 256, 0, stream>>>(partials, offsets);
    scan_final<<<NPART, 256, 0, stream>>>(cnt, offsets, rowptr);
    fill_kernel<<<(N_EDGES + 255) / 256, 256, 0, stream>>>(src, dst, rowptr, cursor, col);

    // weight prep + x cast
    wsplit_kernel<128><<<(128 * 256 + 255) / 256, 256, 0, stream>>>(Ws0, Wn0, Wt0_hi, Wt0_lo);
    wsplit_kernel<128><<<(128 * 256 + 255) / 256, 256, 0, stream>>>(Ws1, Wn1, Wt1_hi, Wt1_lo);
    wsplit_kernel<64> <<<(64 * 256 + 255) / 256, 256, 0, stream>>>(Ws2, Wn2, Wt2_hi, Wt2_lo);
    cast_bf16_kernel<<<(N_NODES * 32 + 255) / 256, 256, 0, stream>>>(x, nb);

    const int AGB = (N_NODES + 3) / 4;        // 12500
    const int MB  = (N_NODES + 127) / 128;    // 391
    dim3 g01(4, MB), g2(2, MB);               // x = col-block (fast), y = row-block

    // layer 0: agg from nb(=x bf16); combine writes hA f32 + nb bf16
    aggregate_kernel<<<AGB, 256, 0, stream>>>(nb, rowptr, col, cnt, agg);
    combine_mfma2<128, true, true><<<g01, 256, 0, stream>>>(x, agg, Wt0_hi, Wt0_lo, b0, hA, nb);
    // layer 1
    aggregate_kernel<<<AGB, 256, 0, stream>>>(nb, rowptr, col, cnt, agg);
    combine_mfma2<128, true, true><<<g01, 256, 0, stream>>>(hA, agg, Wt1_hi, Wt1_lo, b1, hB, nb);
    // layer 2
    aggregate_kernel<<<AGB, 256, 0, stream>>>(nb, rowptr, col, cnt, agg);
    combine_mfma2<64, false, false><<<g2, 256, 0, stream>>>(hB, agg, Wt2_hi, Wt2_lo, b2, out, nullptr);
}

// Round 6
// 281.530 us; speedup vs baseline: 1.3641x; 1.0669x over previous
//
#include <hip/hip_runtime.h>

#define N_NODES 50000
#define N_EDGES 600000
#define NPART 196   // ceil(50000/256)
#define MBLK 391    // ceil(50000/128)

using f32x2  = __attribute__((ext_vector_type(2))) float;
using f32x4  = __attribute__((ext_vector_type(4))) float;
using bf16x8 = __attribute__((ext_vector_type(8))) short;

__device__ inline ushort f2bf(float f) {
    uint32_t u = __builtin_bit_cast(uint32_t, f);
    uint32_t r = (u + 0x7FFFu + ((u >> 16) & 1u)) >> 16;
    return (ushort)r;
}
__device__ inline float bf2f(ushort h) {
    uint32_t u = ((uint32_t)h) << 16;
    return __builtin_bit_cast(float, u);
}

// ---------------------------------------------------------------- CSR build

__global__ void count_kernel(const int* __restrict__ dst, int* __restrict__ cnt) {
    int e = blockIdx.x * blockDim.x + threadIdx.x;
    if (e < N_EDGES) atomicAdd(&cnt[dst[e]], 1);
}

__global__ void scan_part(const int* __restrict__ cnt, int* __restrict__ partials) {
    __shared__ int sm[256];
    int b = blockIdx.x, t = threadIdx.x;
    int i = b * 256 + t;
    sm[t] = (i < N_NODES) ? cnt[i] : 0;
    __syncthreads();
    for (int off = 128; off > 0; off >>= 1) {
        if (t < off) sm[t] += sm[t + off];
        __syncthreads();
    }
    if (t == 0) partials[b] = sm[0];
}

__global__ void scan_mid(const int* __restrict__ partials, int* __restrict__ offsets) {
    __shared__ int sm[256];
    int t = threadIdx.x;
    int v = (t < NPART) ? partials[t] : 0;
    sm[t] = v;
    __syncthreads();
    for (int off = 1; off < 256; off <<= 1) {
        int u = (t >= off) ? sm[t - off] : 0;
        __syncthreads();
        sm[t] += u;
        __syncthreads();
    }
    if (t < NPART) offsets[t] = sm[t] - v;   // exclusive prefix
}

__global__ void scan_final(const int* __restrict__ cnt, const int* __restrict__ offsets,
                           int* __restrict__ rowptr) {
    __shared__ int sm[256];
    int b = blockIdx.x, t = threadIdx.x;
    int i = b * 256 + t;
    int v = (i < N_NODES) ? cnt[i] : 0;
    sm[t] = v;
    __syncthreads();
    for (int off = 1; off < 256; off <<= 1) {
        int u = (t >= off) ? sm[t - off] : 0;
        __syncthreads();
        sm[t] += u;
        __syncthreads();
    }
    if (i < N_NODES) rowptr[i + 1] = sm[t] + offsets[b];
    if (i == 0) rowptr[0] = 0;
}

__global__ void fill_kernel(const int* __restrict__ src, const int* __restrict__ dst,
                            const int* __restrict__ rowptr, int* __restrict__ cursor,
                            int* __restrict__ col) {
    int e = blockIdx.x * blockDim.x + threadIdx.x;
    if (e < N_EDGES) {
        int d = dst[e];
        int pos = atomicAdd(&cursor[d], 1);
        col[rowptr[d] + pos] = src[e];
    }
}

// ---------------------------------------------------------------- x -> hi/lo split

__global__ void cast_split_kernel(const float* __restrict__ in,
                                  ushort* __restrict__ hi, ushort* __restrict__ lo) {
    int i = blockIdx.x * 256 + threadIdx.x;      // 4 floats per thread
    if (i >= N_NODES * 32) return;
    f32x4 v = *(const f32x4*)(in + (size_t)i * 4);
    ushort4 h4, l4;
    float vv[4] = {v[0], v[1], v[2], v[3]};
    ushort hb;
    hb = f2bf(vv[0]); h4.x = hb; l4.x = f2bf(vv[0] - bf2f(hb));
    hb = f2bf(vv[1]); h4.y = hb; l4.y = f2bf(vv[1] - bf2f(hb));
    hb = f2bf(vv[2]); h4.z = hb; l4.z = f2bf(vv[2] - bf2f(hb));
    hb = f2bf(vv[3]); h4.w = hb; l4.w = f2bf(vv[3] - bf2f(hb));
    *(ushort4*)(hi + (size_t)i * 4) = h4;
    *(ushort4*)(lo + (size_t)i * 4) = l4;
}

// ---------------------------------------------------------------- aggregate (bf16 gather)
// one wave per node; lane loads 1 dword = 2 bf16; f32 accumulate;
// writes agg as hi/lo bf16 split (matches combine's in-kernel split exactly)

__global__ __launch_bounds__(256) void aggregate_kernel(
    const ushort* __restrict__ hb, const int* __restrict__ rowptr,
    const int* __restrict__ col, const int* __restrict__ cnt,
    uint32_t* __restrict__ aggh, uint32_t* __restrict__ aggl)
{
    int node = blockIdx.x * 4 + (threadIdx.x >> 6);
    int l = threadIdx.x & 63;
    if (node >= N_NODES) return;
    int beg = rowptr[node], end = rowptr[node + 1];
    float sx = 0.f, sy = 0.f;
    int e = beg;
    for (; e + 3 < end; e += 4) {
        int c0 = col[e], c1 = col[e + 1], c2 = col[e + 2], c3 = col[e + 3];
        uint32_t u0 = *(const uint32_t*)&hb[(size_t)c0 * 128 + l * 2];
        uint32_t u1 = *(const uint32_t*)&hb[(size_t)c1 * 128 + l * 2];
        uint32_t u2 = *(const uint32_t*)&hb[(size_t)c2 * 128 + l * 2];
        uint32_t u3 = *(const uint32_t*)&hb[(size_t)c3 * 128 + l * 2];
        sx += __builtin_bit_cast(float, u0 << 16) + __builtin_bit_cast(float, u1 << 16)
            + __builtin_bit_cast(float, u2 << 16) + __builtin_bit_cast(float, u3 << 16);
        sy += __builtin_bit_cast(float, u0 & 0xffff0000u) + __builtin_bit_cast(float, u1 & 0xffff0000u)
            + __builtin_bit_cast(float, u2 & 0xffff0000u) + __builtin_bit_cast(float, u3 & 0xffff0000u);
    }
    for (; e < end; ++e) {
        uint32_t u = *(const uint32_t*)&hb[(size_t)col[e] * 128 + l * 2];
        sx += __builtin_bit_cast(float, u << 16);
        sy += __builtin_bit_cast(float, u & 0xffff0000u);
    }
    float dinv = 1.0f / (float)max(cnt[node], 1);
    float a0 = sx * dinv, a1 = sy * dinv;
    ushort h0 = f2bf(a0), h1 = f2bf(a1);
    ushort l0 = f2bf(a0 - bf2f(h0)), l1 = f2bf(a1 - bf2f(h1));
    aggh[(size_t)node * 64 + l] = (uint32_t)h0 | ((uint32_t)h1 << 16);
    aggl[(size_t)node * 64 + l] = (uint32_t)l0 | ((uint32_t)l1 << 16);
}

// ---------------------------------------------------------------- weight prep
// Wt_hi/Wt_lo: [NOUT][256] bf16 (transposed + split); k<128 -> Wself, k>=128 -> Wneigh

template <int NOUT>
__global__ void wsplit_kernel(const float* __restrict__ Ws, const float* __restrict__ Wn,
                              short* __restrict__ Wt_hi, short* __restrict__ Wt_lo) {
    int idx = blockIdx.x * 256 + threadIdx.x;      // c*256 + k
    if (idx >= NOUT * 256) return;
    int c = idx >> 8, k = idx & 255;
    float v = (k < 128) ? Ws[(size_t)k * NOUT + c] : Wn[(size_t)(k - 128) * NOUT + c];
    ushort hi = f2bf(v);
    float lo = v - bf2f(hi);
    Wt_hi[idx] = (short)hi;
    Wt_lo[idx] = (short)f2bf(lo);
}

// ---------------------------------------------------------------- combine GEMM v3
// out[n,j] = relu([h|agg][n,:] @ Wcat[:,j] + b), K=256, split-bf16 (3 MFMA).
// A read directly from pre-split global hi/lo bf16 (no conversion VALU).
// B staged in LDS once; zero k-loop barriers. XCD-aware 1D block mapping:
// xcd = id&7 owns 49 contiguous row-blocks x CB col-blocks -> A panels are
// fetched once per (shared) L2 instead of once per col-block's XCD.

template <int NOUT, int CB, bool RELU, bool FINAL>
__global__ __launch_bounds__(256) void combine_mfma3(
    const ushort* __restrict__ nbh, const ushort* __restrict__ nbl,
    const ushort* __restrict__ aggh, const ushort* __restrict__ aggl,
    const short* __restrict__ Wth, const short* __restrict__ Wtl,
    const float* __restrict__ bias, float* __restrict__ out,
    ushort* __restrict__ oh, ushort* __restrict__ ol)
{
    __shared__ __attribute__((aligned(16))) short Bh[32 * 33 * 8];
    __shared__ __attribute__((aligned(16))) short Bl[32 * 33 * 8];

    // ---- XCD-aware mapping: id -> (rowblk, colblk)
    const int id  = blockIdx.x;          // grid = 392*CB
    const int xcd = id & 7;
    const int k   = id >> 3;             // 0 .. 49*CB-1
    const int rowblk = xcd * 49 + k / CB;
    const int cb     = k % CB;
    if (rowblk >= MBLK) return;          // uniform across block
    const int row0    = rowblk * 128;
    const int colbase = cb * 32;

    const int tid  = threadIdx.x;
    const int lane = tid & 63;
    const int wave = tid >> 6;
    const int rr = lane & 15;
    const int kq = lane >> 4;            // 0..3

    // ---- stage B once
    {
        int col = tid >> 3;
        int kc0 = (tid & 7) * 4;
        const short* gh = Wth + (size_t)(colbase + col) * 256 + kc0 * 8;
        const short* gl = Wtl + (size_t)(colbase + col) * 256 + kc0 * 8;
        #pragma unroll
        for (int j = 0; j < 4; ++j) {
            ((bf16x8*)Bh)[col * 33 + kc0 + j] = *(const bf16x8*)(gh + j * 8);
            ((bf16x8*)Bl)[col * 33 + kc0 + j] = *(const bf16x8*)(gl + j * 8);
        }
    }
    __syncthreads();

    f32x4 acc[2][2];
    #pragma unroll
    for (int i = 0; i < 2; ++i)
        #pragma unroll
        for (int j = 0; j < 2; ++j)
            acc[i][j] = (f32x4){0.f, 0.f, 0.f, 0.f};

    #pragma unroll
    for (int ks = 0; ks < 8; ++ks) {
        const ushort* bh_base = (ks < 4) ? nbh : aggh;
        const ushort* bl_base = (ks < 4) ? nbl : aggl;
        const int kf = (ks & 3) * 32 + kq * 8;

        bf16x8 ah[2], al[2];
        #pragma unroll
        for (int mi = 0; mi < 2; ++mi) {
            int row = row0 + wave * 32 + mi * 16 + rr;
            if (row < N_NODES) {
                ah[mi] = *(const bf16x8*)(bh_base + (size_t)row * 128 + kf);
                al[mi] = *(const bf16x8*)(bl_base + (size_t)row * 128 + kf);
            } else {
                ah[mi] = (bf16x8){0,0,0,0,0,0,0,0};
                al[mi] = (bf16x8){0,0,0,0,0,0,0,0};
            }
        }

        #pragma unroll
        for (int nj = 0; nj < 2; ++nj) {
            int colL = nj * 16 + rr;
            int kc = ks * 4 + kq;
            bf16x8 bh = ((const bf16x8*)Bh)[colL * 33 + kc];
            bf16x8 bl = ((const bf16x8*)Bl)[colL * 33 + kc];
            #pragma unroll
            for (int mi = 0; mi < 2; ++mi) {
                acc[mi][nj] = __builtin_amdgcn_mfma_f32_16x16x32_bf16(ah[mi], bh, acc[mi][nj], 0, 0, 0);
                acc[mi][nj] = __builtin_amdgcn_mfma_f32_16x16x32_bf16(al[mi], bh, acc[mi][nj], 0, 0, 0);
                acc[mi][nj] = __builtin_amdgcn_mfma_f32_16x16x32_bf16(ah[mi], bl, acc[mi][nj], 0, 0, 0);
            }
        }
    }

    // ---- epilogue: D col=lane&15, row=(lane>>4)*4+r
    const int rg = lane >> 4;
    #pragma unroll
    for (int nj = 0; nj < 2; ++nj) {
        int colg = colbase + nj * 16 + rr;
        float bv = bias[colg];
        #pragma unroll
        for (int mi = 0; mi < 2; ++mi) {
            #pragma unroll
            for (int r = 0; r < 4; ++r) {
                int row = row0 + wave * 32 + mi * 16 + rg * 4 + r;
                if (row < N_NODES) {
                    float v = acc[mi][nj][r] + bv;
                    if (RELU) v = fmaxf(v, 0.f);
                    if (FINAL) {
                        out[(size_t)row * NOUT + colg] = v;
                    } else {
                        ushort hb = f2bf(v);
                        oh[(size_t)row * NOUT + colg] = hb;
                        ol[(size_t)row * NOUT + colg] = f2bf(v - bf2f(hb));
                    }
                }
            }
        }
    }
}

// ---------------------------------------------------------------- launch

extern "C" void kernel_launch(void* const* d_in, const int* in_sizes, int n_in,
                              void* d_out, int out_size, void* d_ws, size_t ws_size,
                              hipStream_t stream) {
    const float* x   = (const float*)d_in[0];
    const int*   src = (const int*)d_in[1];
    const int*   dst = (const int*)d_in[2];
    const float* Ws0 = (const float*)d_in[3];
    const float* Wn0 = (const float*)d_in[4];
    const float* b0  = (const float*)d_in[5];
    const float* Ws1 = (const float*)d_in[6];
    const float* Wn1 = (const float*)d_in[7];
    const float* b1  = (const float*)d_in[8];
    const float* Ws2 = (const float*)d_in[9];
    const float* Wn2 = (const float*)d_in[10];
    const float* b2  = (const float*)d_in[11];
    float* out = (float*)d_out;

    char* p = (char*)d_ws;
    auto alloc = [&](size_t bytes) {
        char* r = p;
        p += (bytes + 255) & ~(size_t)255;
        return r;
    };
    int*      cnt      = (int*)alloc((size_t)N_NODES * 4);
    int*      cursor   = (int*)alloc((size_t)N_NODES * 4);
    int*      rowptr   = (int*)alloc((size_t)(N_NODES + 1) * 4);
    int*      col      = (int*)alloc((size_t)N_EDGES * 4);
    int*      partials = (int*)alloc((size_t)NPART * 4);
    int*      offsets  = (int*)alloc((size_t)NPART * 4);
    uint32_t* aggh     = (uint32_t*)alloc((size_t)N_NODES * 64 * 4);
    uint32_t* aggl     = (uint32_t*)alloc((size_t)N_NODES * 64 * 4);
    ushort*   nbh0     = (ushort*)alloc((size_t)N_NODES * 128 * 2);
    ushort*   nbl0     = (ushort*)alloc((size_t)N_NODES * 128 * 2);
    ushort*   nbh1     = (ushort*)alloc((size_t)N_NODES * 128 * 2);
    ushort*   nbl1     = (ushort*)alloc((size_t)N_NODES * 128 * 2);
    short*    Wt0_hi   = (short*)alloc((size_t)128 * 256 * 2);
    short*    Wt0_lo   = (short*)alloc((size_t)128 * 256 * 2);
    short*    Wt1_hi   = (short*)alloc((size_t)128 * 256 * 2);
    short*    Wt1_lo   = (short*)alloc((size_t)128 * 256 * 2);
    short*    Wt2_hi   = (short*)alloc((size_t)64 * 256 * 2);
    short*    Wt2_lo   = (short*)alloc((size_t)64 * 256 * 2);

    hipMemsetAsync(cnt, 0, (size_t)N_NODES * 4, stream);
    hipMemsetAsync(cursor, 0, (size_t)N_NODES * 4, stream);

    // CSR build
    count_kernel<<<(N_EDGES + 255) / 256, 256, 0, stream>>>(dst, cnt);
    scan_part <<<NPART, 256, 0, stream>>>(cnt, partials);
    scan_mid  <<<1, 256, 0, stream>>>(partials, offsets);
    scan_final<<<NPART, 256, 0, stream>>>(cnt, offsets, rowptr);
    fill_kernel<<<(N_EDGES + 255) / 256, 256, 0, stream>>>(src, dst, rowptr, cursor, col);

    // weight prep + x split
    wsplit_kernel<128><<<(128 * 256 + 255) / 256, 256, 0, stream>>>(Ws0, Wn0, Wt0_hi, Wt0_lo);
    wsplit_kernel<128><<<(128 * 256 + 255) / 256, 256, 0, stream>>>(Ws1, Wn1, Wt1_hi, Wt1_lo);
    wsplit_kernel<64> <<<(64 * 256 + 255) / 256, 256, 0, stream>>>(Ws2, Wn2, Wt2_hi, Wt2_lo);
    cast_split_kernel<<<(N_NODES * 32 + 255) / 256, 256, 0, stream>>>(x, nbh0, nbl0);

    const int AGB = (N_NODES + 3) / 4;        // 12500

    // layer 0: agg from nbh0(=x hi); combine reads nbh0/nbl0, writes nbh1/nbl1
    aggregate_kernel<<<AGB, 256, 0, stream>>>(nbh0, rowptr, col, cnt, aggh, aggl);
    combine_mfma3<128, 4, true, false><<<392 * 4, 256, 0, stream>>>(
        nbh0, nbl0, (const ushort*)aggh, (const ushort*)aggl, Wt0_hi, Wt0_lo, b0, nullptr, nbh1, nbl1);
    // layer 1: agg from nbh1; combine writes nbh0/nbl0
    aggregate_kernel<<<AGB, 256, 0, stream>>>(nbh1, rowptr, col, cnt, aggh, aggl);
    combine_mfma3<128, 4, true, false><<<392 * 4, 256, 0, stream>>>(
        nbh1, nbl1, (const ushort*)aggh, (const ushort*)aggl, Wt1_hi, Wt1_lo, b1, nullptr, nbh0, nbl0);
    // layer 2: agg from nbh0; combine writes f32 out
    aggregate_kernel<<<AGB, 256, 0, stream>>>(nbh0, rowptr, col, cnt, aggh, aggl);
    combine_mfma3<64, 2, false, true><<<392 * 2, 256, 0, stream>>>(
        nbh0, nbl0, (const ushort*)aggh, (const ushort*)aggl, Wt2_hi, Wt2_lo, b2, out, nullptr, nullptr);
}

// Round 7
// 280.603 us; speedup vs baseline: 1.3686x; 1.0033x over previous
//
#include <hip/hip_runtime.h>

#define N_NODES 50000
#define PADROWS 50048   // 391*128, lets combine load A branchlessly
#define N_EDGES 600000
#define NPART 196   // ceil(50000/256)
#define MBLK 391    // ceil(50000/128)

using f32x2  = __attribute__((ext_vector_type(2))) float;
using f32x4  = __attribute__((ext_vector_type(4))) float;
using bf16x8 = __attribute__((ext_vector_type(8))) short;

__device__ inline ushort f2bf(float f) {
    uint32_t u = __builtin_bit_cast(uint32_t, f);
    uint32_t r = (u + 0x7FFFu + ((u >> 16) & 1u)) >> 16;
    return (ushort)r;
}
__device__ inline float bf2f(ushort h) {
    uint32_t u = ((uint32_t)h) << 16;
    return __builtin_bit_cast(float, u);
}

// ---------------------------------------------------------------- zero (replaces hipMemsetAsync: rocclr fill was 40us/dispatch)

__global__ void zero2_kernel(int* __restrict__ a, int* __restrict__ b) {
    int i = blockIdx.x * 256 + threadIdx.x;
    if (i < N_NODES) { a[i] = 0; b[i] = 0; }
}

// ---------------------------------------------------------------- CSR build

__global__ void count_kernel(const int* __restrict__ dst, int* __restrict__ cnt) {
    int e = blockIdx.x * blockDim.x + threadIdx.x;
    if (e < N_EDGES) atomicAdd(&cnt[dst[e]], 1);
}

__global__ void scan_part(const int* __restrict__ cnt, int* __restrict__ partials) {
    __shared__ int sm[256];
    int b = blockIdx.x, t = threadIdx.x;
    int i = b * 256 + t;
    sm[t] = (i < N_NODES) ? cnt[i] : 0;
    __syncthreads();
    for (int off = 128; off > 0; off >>= 1) {
        if (t < off) sm[t] += sm[t + off];
        __syncthreads();
    }
    if (t == 0) partials[b] = sm[0];
}

__global__ void scan_mid(const int* __restrict__ partials, int* __restrict__ offsets) {
    __shared__ int sm[256];
    int t = threadIdx.x;
    int v = (t < NPART) ? partials[t] : 0;
    sm[t] = v;
    __syncthreads();
    for (int off = 1; off < 256; off <<= 1) {
        int u = (t >= off) ? sm[t - off] : 0;
        __syncthreads();
        sm[t] += u;
        __syncthreads();
    }
    if (t < NPART) offsets[t] = sm[t] - v;   // exclusive prefix
}

__global__ void scan_final(const int* __restrict__ cnt, const int* __restrict__ offsets,
                           int* __restrict__ rowptr) {
    __shared__ int sm[256];
    int b = blockIdx.x, t = threadIdx.x;
    int i = b * 256 + t;
    int v = (i < N_NODES) ? cnt[i] : 0;
    sm[t] = v;
    __syncthreads();
    for (int off = 1; off < 256; off <<= 1) {
        int u = (t >= off) ? sm[t - off] : 0;
        __syncthreads();
        sm[t] += u;
        __syncthreads();
    }
    if (i < N_NODES) rowptr[i + 1] = sm[t] + offsets[b];
    if (i == 0) rowptr[0] = 0;
}

__global__ void fill_kernel(const int* __restrict__ src, const int* __restrict__ dst,
                            const int* __restrict__ rowptr, int* __restrict__ cursor,
                            int* __restrict__ col) {
    int e = blockIdx.x * blockDim.x + threadIdx.x;
    if (e < N_EDGES) {
        int d = dst[e];
        int pos = atomicAdd(&cursor[d], 1);
        col[rowptr[d] + pos] = src[e];
    }
}

// ---------------------------------------------------------------- x -> hi/lo split

__global__ void cast_split_kernel(const float* __restrict__ in,
                                  ushort* __restrict__ hi, ushort* __restrict__ lo) {
    int i = blockIdx.x * 256 + threadIdx.x;      // 4 floats per thread
    if (i >= N_NODES * 32) return;
    f32x4 v = *(const f32x4*)(in + (size_t)i * 4);
    ushort4 h4, l4;
    float vv[4] = {v[0], v[1], v[2], v[3]};
    ushort hb;
    hb = f2bf(vv[0]); h4.x = hb; l4.x = f2bf(vv[0] - bf2f(hb));
    hb = f2bf(vv[1]); h4.y = hb; l4.y = f2bf(vv[1] - bf2f(hb));
    hb = f2bf(vv[2]); h4.z = hb; l4.z = f2bf(vv[2] - bf2f(hb));
    hb = f2bf(vv[3]); h4.w = hb; l4.w = f2bf(vv[3] - bf2f(hb));
    *(ushort4*)(hi + (size_t)i * 4) = h4;
    *(ushort4*)(lo + (size_t)i * 4) = l4;
}

// ---------------------------------------------------------------- aggregate (bf16 gather)
// one wave per node; lane loads 1 dword = 2 bf16; f32 accumulate;
// writes agg as hi/lo bf16 split (matches combine's in-kernel split exactly)

__global__ __launch_bounds__(256) void aggregate_kernel(
    const ushort* __restrict__ hb, const int* __restrict__ rowptr,
    const int* __restrict__ col, const int* __restrict__ cnt,
    uint32_t* __restrict__ aggh, uint32_t* __restrict__ aggl)
{
    int node = blockIdx.x * 4 + (threadIdx.x >> 6);
    int l = threadIdx.x & 63;
    if (node >= N_NODES) return;
    int beg = rowptr[node], end = rowptr[node + 1];
    float sx = 0.f, sy = 0.f;
    int e = beg;
    for (; e + 3 < end; e += 4) {
        int c0 = col[e], c1 = col[e + 1], c2 = col[e + 2], c3 = col[e + 3];
        uint32_t u0 = *(const uint32_t*)&hb[(size_t)c0 * 128 + l * 2];
        uint32_t u1 = *(const uint32_t*)&hb[(size_t)c1 * 128 + l * 2];
        uint32_t u2 = *(const uint32_t*)&hb[(size_t)c2 * 128 + l * 2];
        uint32_t u3 = *(const uint32_t*)&hb[(size_t)c3 * 128 + l * 2];
        sx += __builtin_bit_cast(float, u0 << 16) + __builtin_bit_cast(float, u1 << 16)
            + __builtin_bit_cast(float, u2 << 16) + __builtin_bit_cast(float, u3 << 16);
        sy += __builtin_bit_cast(float, u0 & 0xffff0000u) + __builtin_bit_cast(float, u1 & 0xffff0000u)
            + __builtin_bit_cast(float, u2 & 0xffff0000u) + __builtin_bit_cast(float, u3 & 0xffff0000u);
    }
    for (; e < end; ++e) {
        uint32_t u = *(const uint32_t*)&hb[(size_t)col[e] * 128 + l * 2];
        sx += __builtin_bit_cast(float, u << 16);
        sy += __builtin_bit_cast(float, u & 0xffff0000u);
    }
    float dinv = 1.0f / (float)max(cnt[node], 1);
    float a0 = sx * dinv, a1 = sy * dinv;
    ushort h0 = f2bf(a0), h1 = f2bf(a1);
    ushort l0 = f2bf(a0 - bf2f(h0)), l1 = f2bf(a1 - bf2f(h1));
    aggh[(size_t)node * 64 + l] = (uint32_t)h0 | ((uint32_t)h1 << 16);
    aggl[(size_t)node * 64 + l] = (uint32_t)l0 | ((uint32_t)l1 << 16);
}

// ---------------------------------------------------------------- weight prep
// Wt_hi/Wt_lo: [NOUT][256] bf16 (transposed + split); k<128 -> Wself, k>=128 -> Wneigh

template <int NOUT>
__global__ void wsplit_kernel(const float* __restrict__ Ws, const float* __restrict__ Wn,
                              short* __restrict__ Wt_hi, short* __restrict__ Wt_lo) {
    int idx = blockIdx.x * 256 + threadIdx.x;      // c*256 + k
    if (idx >= NOUT * 256) return;
    int c = idx >> 8, k = idx & 255;
    float v = (k < 128) ? Ws[(size_t)k * NOUT + c] : Wn[(size_t)(k - 128) * NOUT + c];
    ushort hi = f2bf(v);
    float lo = v - bf2f(hi);
    Wt_hi[idx] = (short)hi;
    Wt_lo[idx] = (short)f2bf(lo);
}

// ---------------------------------------------------------------- combine GEMM v4
// out[n,j] = relu([h|agg][n,:] @ Wcat[:,j] + b), K=256, split-bf16 (3 MFMA).
// A from pre-split global hi/lo bf16, BRANCHLESS (buffers padded to PADROWS),
// double-buffered register prefetch (ks+1 issued before ks's MFMAs).
// B staged in LDS once; zero k-loop barriers; XCD-aware 1D block mapping.

template <int NOUT, int CB, bool RELU, bool FINAL>
__global__ __launch_bounds__(256) void combine_mfma4(
    const ushort* __restrict__ nbh, const ushort* __restrict__ nbl,
    const ushort* __restrict__ aggh, const ushort* __restrict__ aggl,
    const short* __restrict__ Wth, const short* __restrict__ Wtl,
    const float* __restrict__ bias, float* __restrict__ out,
    ushort* __restrict__ oh, ushort* __restrict__ ol)
{
    __shared__ __attribute__((aligned(16))) short Bh[32 * 33 * 8];
    __shared__ __attribute__((aligned(16))) short Bl[32 * 33 * 8];

    // ---- XCD-aware mapping: id -> (rowblk, colblk)
    const int id  = blockIdx.x;          // grid = 392*CB
    const int xcd = id & 7;
    const int k   = id >> 3;             // 0 .. 49*CB-1
    const int rowblk = xcd * 49 + k / CB;
    const int cb     = k % CB;
    if (rowblk >= MBLK) return;          // uniform across block
    const int row0    = rowblk * 128;
    const int colbase = cb * 32;

    const int tid  = threadIdx.x;
    const int lane = tid & 63;
    const int wave = tid >> 6;
    const int rr = lane & 15;
    const int kq = lane >> 4;            // 0..3

    // ---- stage B once
    {
        int col = tid >> 3;
        int kc0 = (tid & 7) * 4;
        const short* gh = Wth + (size_t)(colbase + col) * 256 + kc0 * 8;
        const short* gl = Wtl + (size_t)(colbase + col) * 256 + kc0 * 8;
        #pragma unroll
        for (int j = 0; j < 4; ++j) {
            ((bf16x8*)Bh)[col * 33 + kc0 + j] = *(const bf16x8*)(gh + j * 8);
            ((bf16x8*)Bl)[col * 33 + kc0 + j] = *(const bf16x8*)(gl + j * 8);
        }
    }

    f32x4 acc[2][2];
    #pragma unroll
    for (int i = 0; i < 2; ++i)
        #pragma unroll
        for (int j = 0; j < 2; ++j)
            acc[i][j] = (f32x4){0.f, 0.f, 0.f, 0.f};

    const size_t arow0 = (size_t)(row0 + wave * 32 + rr) * 128;
    const size_t arow1 = arow0 + (size_t)16 * 128;

    bf16x8 ah[2][2], al[2][2];   // [parity][mi] — all indices compile-time

#define LOADA(KS, P) do {                                                   \
        const ushort* bh_ = ((KS) < 4) ? nbh : aggh;                        \
        const ushort* bl_ = ((KS) < 4) ? nbl : aggl;                        \
        const int kf_ = ((KS) & 3) * 32 + kq * 8;                           \
        ah[P][0] = *(const bf16x8*)(bh_ + arow0 + kf_);                     \
        al[P][0] = *(const bf16x8*)(bl_ + arow0 + kf_);                     \
        ah[P][1] = *(const bf16x8*)(bh_ + arow1 + kf_);                     \
        al[P][1] = *(const bf16x8*)(bl_ + arow1 + kf_);                     \
    } while (0)

    LOADA(0, 0);
    __syncthreads();   // B ready (A prefetch already in flight)

    #pragma unroll
    for (int ks = 0; ks < 8; ++ks) {
        if (ks < 7) {
            if ((ks & 1) == 0) LOADA(ks + 1, 1);
            else               LOADA(ks + 1, 0);
        }
        const int p = ks & 1;   // compile-time under full unroll
        #pragma unroll
        for (int nj = 0; nj < 2; ++nj) {
            int colL = nj * 16 + rr;
            int kc = ks * 4 + kq;
            bf16x8 bh = ((const bf16x8*)Bh)[colL * 33 + kc];
            bf16x8 bl = ((const bf16x8*)Bl)[colL * 33 + kc];
            #pragma unroll
            for (int mi = 0; mi < 2; ++mi) {
                acc[mi][nj] = __builtin_amdgcn_mfma_f32_16x16x32_bf16(ah[p][mi], bh, acc[mi][nj], 0, 0, 0);
                acc[mi][nj] = __builtin_amdgcn_mfma_f32_16x16x32_bf16(al[p][mi], bh, acc[mi][nj], 0, 0, 0);
                acc[mi][nj] = __builtin_amdgcn_mfma_f32_16x16x32_bf16(ah[p][mi], bl, acc[mi][nj], 0, 0, 0);
            }
        }
    }
#undef LOADA

    // ---- epilogue: D col=lane&15, row=(lane>>4)*4+r
    const int rg = lane >> 4;
    #pragma unroll
    for (int nj = 0; nj < 2; ++nj) {
        int colg = colbase + nj * 16 + rr;
        float bv = bias[colg];
        #pragma unroll
        for (int mi = 0; mi < 2; ++mi) {
            #pragma unroll
            for (int r = 0; r < 4; ++r) {
                int row = row0 + wave * 32 + mi * 16 + rg * 4 + r;
                if (row < N_NODES) {
                    float v = acc[mi][nj][r] + bv;
                    if (RELU) v = fmaxf(v, 0.f);
                    if (FINAL) {
                        out[(size_t)row * NOUT + colg] = v;
                    } else {
                        ushort hb = f2bf(v);
                        oh[(size_t)row * NOUT + colg] = hb;
                        ol[(size_t)row * NOUT + colg] = f2bf(v - bf2f(hb));
                    }
                }
            }
        }
    }
}

// ---------------------------------------------------------------- launch

extern "C" void kernel_launch(void* const* d_in, const int* in_sizes, int n_in,
                              void* d_out, int out_size, void* d_ws, size_t ws_size,
                              hipStream_t stream) {
    const float* x   = (const float*)d_in[0];
    const int*   src = (const int*)d_in[1];
    const int*   dst = (const int*)d_in[2];
    const float* Ws0 = (const float*)d_in[3];
    const float* Wn0 = (const float*)d_in[4];
    const float* b0  = (const float*)d_in[5];
    const float* Ws1 = (const float*)d_in[6];
    const float* Wn1 = (const float*)d_in[7];
    const float* b1  = (const float*)d_in[8];
    const float* Ws2 = (const float*)d_in[9];
    const float* Wn2 = (const float*)d_in[10];
    const float* b2  = (const float*)d_in[11];
    float* out = (float*)d_out;

    char* p = (char*)d_ws;
    auto alloc = [&](size_t bytes) {
        char* r = p;
        p += (bytes + 255) & ~(size_t)255;
        return r;
    };
    int*      cnt      = (int*)alloc((size_t)N_NODES * 4);
    int*      cursor   = (int*)alloc((size_t)N_NODES * 4);
    int*      rowptr   = (int*)alloc((size_t)(N_NODES + 1) * 4);
    int*      col      = (int*)alloc((size_t)N_EDGES * 4);
    int*      partials = (int*)alloc((size_t)NPART * 4);
    int*      offsets  = (int*)alloc((size_t)NPART * 4);
    uint32_t* aggh     = (uint32_t*)alloc((size_t)PADROWS * 64 * 4);
    uint32_t* aggl     = (uint32_t*)alloc((size_t)PADROWS * 64 * 4);
    ushort*   nbh0     = (ushort*)alloc((size_t)PADROWS * 128 * 2);
    ushort*   nbl0     = (ushort*)alloc((size_t)PADROWS * 128 * 2);
    ushort*   nbh1     = (ushort*)alloc((size_t)PADROWS * 128 * 2);
    ushort*   nbl1     = (ushort*)alloc((size_t)PADROWS * 128 * 2);
    short*    Wt0_hi   = (short*)alloc((size_t)128 * 256 * 2);
    short*    Wt0_lo   = (short*)alloc((size_t)128 * 256 * 2);
    short*    Wt1_hi   = (short*)alloc((size_t)128 * 256 * 2);
    short*    Wt1_lo   = (short*)alloc((size_t)128 * 256 * 2);
    short*    Wt2_hi   = (short*)alloc((size_t)64 * 256 * 2);
    short*    Wt2_lo   = (short*)alloc((size_t)64 * 256 * 2);

    // CSR build (zero2_kernel replaces the two 40us rocclr fills)
    zero2_kernel<<<NPART, 256, 0, stream>>>(cnt, cursor);
    count_kernel<<<(N_EDGES + 255) / 256, 256, 0, stream>>>(dst, cnt);
    scan_part <<<NPART, 256, 0, stream>>>(cnt, partials);
    scan_mid  <<<1, 256, 0, stream>>>(partials, offsets);
    scan_final<<<NPART, 256, 0, stream>>>(cnt, offsets, rowptr);
    fill_kernel<<<(N_EDGES + 255) / 256, 256, 0, stream>>>(src, dst, rowptr, cursor, col);

    // weight prep + x split
    wsplit_kernel<128><<<(128 * 256 + 255) / 256, 256, 0, stream>>>(Ws0, Wn0, Wt0_hi, Wt0_lo);
    wsplit_kernel<128><<<(128 * 256 + 255) / 256, 256, 0, stream>>>(Ws1, Wn1, Wt1_hi, Wt1_lo);
    wsplit_kernel<64> <<<(64 * 256 + 255) / 256, 256, 0, stream>>>(Ws2, Wn2, Wt2_hi, Wt2_lo);
    cast_split_kernel<<<(N_NODES * 32 + 255) / 256, 256, 0, stream>>>(x, nbh0, nbl0);

    const int AGB = (N_NODES + 3) / 4;        // 12500

    // layer 0: agg from nbh0(=x hi); combine reads nbh0/nbl0, writes nbh1/nbl1
    aggregate_kernel<<<AGB, 256, 0, stream>>>(nbh0, rowptr, col, cnt, aggh, aggl);
    combine_mfma4<128, 4, true, false><<<392 * 4, 256, 0, stream>>>(
        nbh0, nbl0, (const ushort*)aggh, (const ushort*)aggl, Wt0_hi, Wt0_lo, b0, nullptr, nbh1, nbl1);
    // layer 1: agg from nbh1; combine writes nbh0/nbl0
    aggregate_kernel<<<AGB, 256, 0, stream>>>(nbh1, rowptr, col, cnt, aggh, aggl);
    combine_mfma4<128, 4, true, false><<<392 * 4, 256, 0, stream>>>(
        nbh1, nbl1, (const ushort*)aggh, (const ushort*)aggl, Wt1_hi, Wt1_lo, b1, nullptr, nbh0, nbl0);
    // layer 2: agg from nbh0; combine writes f32 out
    aggregate_kernel<<<AGB, 256, 0, stream>>>(nbh0, rowptr, col, cnt, aggh, aggl);
    combine_mfma4<64, 2, false, true><<<392 * 2, 256, 0, stream>>>(
        nbh0, nbl0, (const ushort*)aggh, (const ushort*)aggl, Wt2_hi, Wt2_lo, b2, out, nullptr, nullptr);
}

// Round 8
// 267.326 us; speedup vs baseline: 1.4366x; 1.0497x over previous
//
#include <hip/hip_runtime.h>

#define N_NODES 50000
#define PADROWS 50048   // 391*128, lets combine load A branchlessly
#define N_EDGES 600000
#define NPART 196   // ceil(50000/256)
#define MBLK 391    // ceil(50000/128)

using f32x2  = __attribute__((ext_vector_type(2))) float;
using f32x4  = __attribute__((ext_vector_type(4))) float;
using bf16x8 = __attribute__((ext_vector_type(8))) short;

__device__ inline ushort f2bf(float f) {
    uint32_t u = __builtin_bit_cast(uint32_t, f);
    uint32_t r = (u + 0x7FFFu + ((u >> 16) & 1u)) >> 16;
    return (ushort)r;
}
__device__ inline float bf2f(ushort h) {
    uint32_t u = ((uint32_t)h) << 16;
    return __builtin_bit_cast(float, u);
}

// ---------------------------------------------------------------- zero

__global__ void zero2_kernel(int* __restrict__ a, int* __restrict__ b) {
    int i = blockIdx.x * 256 + threadIdx.x;
    if (i < N_NODES) { a[i] = 0; b[i] = 0; }
}

// ---------------------------------------------------------------- CSR build

__global__ void count_kernel(const int* __restrict__ dst, int* __restrict__ cnt) {
    int e = blockIdx.x * blockDim.x + threadIdx.x;
    if (e < N_EDGES) atomicAdd(&cnt[dst[e]], 1);
}

__global__ void scan_part(const int* __restrict__ cnt, int* __restrict__ partials) {
    __shared__ int sm[256];
    int b = blockIdx.x, t = threadIdx.x;
    int i = b * 256 + t;
    sm[t] = (i < N_NODES) ? cnt[i] : 0;
    __syncthreads();
    for (int off = 128; off > 0; off >>= 1) {
        if (t < off) sm[t] += sm[t + off];
        __syncthreads();
    }
    if (t == 0) partials[b] = sm[0];
}

__global__ void scan_mid(const int* __restrict__ partials, int* __restrict__ offsets) {
    __shared__ int sm[256];
    int t = threadIdx.x;
    int v = (t < NPART) ? partials[t] : 0;
    sm[t] = v;
    __syncthreads();
    for (int off = 1; off < 256; off <<= 1) {
        int u = (t >= off) ? sm[t - off] : 0;
        __syncthreads();
        sm[t] += u;
        __syncthreads();
    }
    if (t < NPART) offsets[t] = sm[t] - v;   // exclusive prefix
}

__global__ void scan_final(const int* __restrict__ cnt, const int* __restrict__ offsets,
                           int* __restrict__ rowptr) {
    __shared__ int sm[256];
    int b = blockIdx.x, t = threadIdx.x;
    int i = b * 256 + t;
    int v = (i < N_NODES) ? cnt[i] : 0;
    sm[t] = v;
    __syncthreads();
    for (int off = 1; off < 256; off <<= 1) {
        int u = (t >= off) ? sm[t - off] : 0;
        __syncthreads();
        sm[t] += u;
        __syncthreads();
    }
    if (i < N_NODES) rowptr[i + 1] = sm[t] + offsets[b];
    if (i == 0) rowptr[0] = 0;
}

__global__ void fill_kernel(const int* __restrict__ src, const int* __restrict__ dst,
                            const int* __restrict__ rowptr, int* __restrict__ cursor,
                            int* __restrict__ col) {
    int e = blockIdx.x * blockDim.x + threadIdx.x;
    if (e < N_EDGES) {
        int d = dst[e];
        int pos = atomicAdd(&cursor[d], 1);
        col[rowptr[d] + pos] = src[e];
    }
}

// ---------------------------------------------------------------- prep: 3x wsplit + x cast, one launch

__device__ inline void wsplit_one(const float* __restrict__ Ws, const float* __restrict__ Wn,
                                  short* __restrict__ Wh, short* __restrict__ Wl,
                                  int nout, int idx) {
    int c = idx >> 8, k = idx & 255;
    float v = (k < 128) ? Ws[(size_t)k * nout + c] : Wn[(size_t)(k - 128) * nout + c];
    ushort hi = f2bf(v);
    Wh[idx] = (short)hi;
    Wl[idx] = (short)f2bf(v - bf2f(hi));
}

__global__ void prep_kernel(const float* __restrict__ Ws0, const float* __restrict__ Wn0,
                            const float* __restrict__ Ws1, const float* __restrict__ Wn1,
                            const float* __restrict__ Ws2, const float* __restrict__ Wn2,
                            const float* __restrict__ x,
                            short* __restrict__ W0h, short* __restrict__ W0l,
                            short* __restrict__ W1h, short* __restrict__ W1l,
                            short* __restrict__ W2h, short* __restrict__ W2l,
                            ushort* __restrict__ nbh, ushort* __restrict__ nbl) {
    int b = blockIdx.x, t = threadIdx.x;
    if (b < 128) {
        wsplit_one(Ws0, Wn0, W0h, W0l, 128, b * 256 + t);
    } else if (b < 256) {
        wsplit_one(Ws1, Wn1, W1h, W1l, 128, (b - 128) * 256 + t);
    } else if (b < 320) {
        wsplit_one(Ws2, Wn2, W2h, W2l, 64, (b - 256) * 256 + t);
    } else {
        int i = (b - 320) * 256 + t;          // 4 floats per thread
        if (i < N_NODES * 32) {
            f32x4 v = *(const f32x4*)(x + (size_t)i * 4);
            ushort4 h4, l4;
            ushort hb;
            hb = f2bf(v[0]); h4.x = hb; l4.x = f2bf(v[0] - bf2f(hb));
            hb = f2bf(v[1]); h4.y = hb; l4.y = f2bf(v[1] - bf2f(hb));
            hb = f2bf(v[2]); h4.z = hb; l4.z = f2bf(v[2] - bf2f(hb));
            hb = f2bf(v[3]); h4.w = hb; l4.w = f2bf(v[3] - bf2f(hb));
            *(ushort4*)(nbh + (size_t)i * 4) = h4;
            *(ushort4*)(nbl + (size_t)i * 4) = l4;
        }
    }
}

// ---------------------------------------------------------------- aggregate (bf16 gather)
// 32 lanes per edge-row (uint2 = 8B = 4 cols/lane); two half-waves process the
// two halves of the edge range concurrently -> 8 rows in flight per wave with
// 4x unroll. Cross-half reduce via shfl_xor(32). deg_inv folded; hi/lo output.

__global__ __launch_bounds__(256) void aggregate_kernel(
    const ushort* __restrict__ hb, const int* __restrict__ rowptr,
    const int* __restrict__ col, const int* __restrict__ cnt,
    uint32_t* __restrict__ aggh, uint32_t* __restrict__ aggl)
{
    int node = blockIdx.x * 4 + (threadIdx.x >> 6);
    int l = threadIdx.x & 63;
    if (node >= N_NODES) return;
    const int half = l >> 5;          // 0 / 1
    const int c    = l & 31;          // uint2 chunk: cols 4c..4c+3

    int beg = rowptr[node], end = rowptr[node + 1];
    int mid = beg + ((end - beg + 1) >> 1);
    int e    = half ? mid : beg;
    int hend = half ? end : mid;

    f32x4 s = {0.f, 0.f, 0.f, 0.f};

#define ACCUM(U) do {                                                        \
        s[0] += __builtin_bit_cast(float, (U).x << 16);                      \
        s[1] += __builtin_bit_cast(float, (U).x & 0xffff0000u);              \
        s[2] += __builtin_bit_cast(float, (U).y << 16);                      \
        s[3] += __builtin_bit_cast(float, (U).y & 0xffff0000u);              \
    } while (0)

    for (; e + 3 < hend; e += 4) {
        uint2 u0 = *(const uint2*)&hb[(size_t)col[e]     * 128 + c * 4];
        uint2 u1 = *(const uint2*)&hb[(size_t)col[e + 1] * 128 + c * 4];
        uint2 u2 = *(const uint2*)&hb[(size_t)col[e + 2] * 128 + c * 4];
        uint2 u3 = *(const uint2*)&hb[(size_t)col[e + 3] * 128 + c * 4];
        ACCUM(u0); ACCUM(u1); ACCUM(u2); ACCUM(u3);
    }
    for (; e < hend; ++e) {
        uint2 u = *(const uint2*)&hb[(size_t)col[e] * 128 + c * 4];
        ACCUM(u);
    }
#undef ACCUM

    // cross-half reduce: lane l and l^32 hold the two partial sums of same cols
    s[0] += __shfl_xor(s[0], 32);
    s[1] += __shfl_xor(s[1], 32);
    s[2] += __shfl_xor(s[2], 32);
    s[3] += __shfl_xor(s[3], 32);

    if (half == 0) {
        float dinv = 1.0f / (float)max(cnt[node], 1);
        float a0 = s[0] * dinv, a1 = s[1] * dinv, a2 = s[2] * dinv, a3 = s[3] * dinv;
        ushort h0 = f2bf(a0), h1 = f2bf(a1), h2 = f2bf(a2), h3 = f2bf(a3);
        ushort l0 = f2bf(a0 - bf2f(h0)), l1 = f2bf(a1 - bf2f(h1));
        ushort l2 = f2bf(a2 - bf2f(h2)), l3 = f2bf(a3 - bf2f(h3));
        uint2 wh = { (uint32_t)h0 | ((uint32_t)h1 << 16), (uint32_t)h2 | ((uint32_t)h3 << 16) };
        uint2 wl = { (uint32_t)l0 | ((uint32_t)l1 << 16), (uint32_t)l2 | ((uint32_t)l3 << 16) };
        ((uint2*)aggh)[(size_t)node * 32 + c] = wh;
        ((uint2*)aggl)[(size_t)node * 32 + c] = wl;
    }
}

// ---------------------------------------------------------------- combine GEMM v5
// out[n,j] = relu([h|agg][n,:] @ Wcat[:,j] + b), K=256, split-bf16 (3 MFMA).
// Depth-2 register pipeline over 3 named buffers; sched_barrier(0) after each
// load cluster pins issue order (prevents the compiler sinking loads to uses —
// round-7 failure mode, visible as VGPR_Count 52). Branchless A (PADROWS).

template <int NOUT, int CB, bool RELU, bool FINAL>
__global__ __launch_bounds__(256) void combine_mfma5(
    const ushort* __restrict__ nbh, const ushort* __restrict__ nbl,
    const ushort* __restrict__ aggh, const ushort* __restrict__ aggl,
    const short* __restrict__ Wth, const short* __restrict__ Wtl,
    const float* __restrict__ bias, float* __restrict__ out,
    ushort* __restrict__ oh, ushort* __restrict__ ol)
{
    __shared__ __attribute__((aligned(16))) short Bh[32 * 33 * 8];
    __shared__ __attribute__((aligned(16))) short Bl[32 * 33 * 8];

    // ---- XCD-aware mapping: id -> (rowblk, colblk); CB col-blocks of one
    // rowblk sit 8 ids apart -> same XCD -> A panel shared in that L2.
    const int id  = blockIdx.x;          // grid = 392*CB
    const int xcd = id & 7;
    const int k   = id >> 3;
    const int rowblk = xcd * 49 + k / CB;
    const int cb     = k % CB;
    if (rowblk >= MBLK) return;
    const int row0    = rowblk * 128;
    const int colbase = cb * 32;

    const int tid  = threadIdx.x;
    const int lane = tid & 63;
    const int wave = tid >> 6;
    const int rr = lane & 15;
    const int kq = lane >> 4;            // 0..3

    const size_t arow0 = (size_t)(row0 + wave * 32 + rr) * 128;
    const size_t arow1 = arow0 + (size_t)16 * 128;

    bf16x8 ah[3][2], al[3][2];           // [buffer][mi], all indices literal

#define LOADA(KS, P) do {                                                   \
        const ushort* bh_ = ((KS) < 4) ? nbh : aggh;                        \
        const ushort* bl_ = ((KS) < 4) ? nbl : aggl;                        \
        const int kf_ = ((KS) & 3) * 32 + kq * 8;                           \
        ah[P][0] = *(const bf16x8*)(bh_ + arow0 + kf_);                     \
        al[P][0] = *(const bf16x8*)(bl_ + arow0 + kf_);                     \
        ah[P][1] = *(const bf16x8*)(bh_ + arow1 + kf_);                     \
        al[P][1] = *(const bf16x8*)(bl_ + arow1 + kf_);                     \
    } while (0)

#define COMPUTE(KS, P) do {                                                 \
        _Pragma("unroll")                                                   \
        for (int nj = 0; nj < 2; ++nj) {                                    \
            int colL = nj * 16 + rr;                                        \
            bf16x8 bh = ((const bf16x8*)Bh)[colL * 33 + (KS) * 4 + kq];     \
            bf16x8 bl = ((const bf16x8*)Bl)[colL * 33 + (KS) * 4 + kq];     \
            acc[0][nj] = __builtin_amdgcn_mfma_f32_16x16x32_bf16(ah[P][0], bh, acc[0][nj], 0, 0, 0); \
            acc[0][nj] = __builtin_amdgcn_mfma_f32_16x16x32_bf16(al[P][0], bh, acc[0][nj], 0, 0, 0); \
            acc[0][nj] = __builtin_amdgcn_mfma_f32_16x16x32_bf16(ah[P][0], bl, acc[0][nj], 0, 0, 0); \
            acc[1][nj] = __builtin_amdgcn_mfma_f32_16x16x32_bf16(ah[P][1], bh, acc[1][nj], 0, 0, 0); \
            acc[1][nj] = __builtin_amdgcn_mfma_f32_16x16x32_bf16(al[P][1], bh, acc[1][nj], 0, 0, 0); \
            acc[1][nj] = __builtin_amdgcn_mfma_f32_16x16x32_bf16(ah[P][1], bl, acc[1][nj], 0, 0, 0); \
        }                                                                   \
    } while (0)

#define SB __builtin_amdgcn_sched_barrier(0)

    // prologue: first two A k-tiles in flight before B staging
    LOADA(0, 0);
    LOADA(1, 1);

    // ---- stage B once
    {
        int col = tid >> 3;
        int kc0 = (tid & 7) * 4;
        const short* gh = Wth + (size_t)(colbase + col) * 256 + kc0 * 8;
        const short* gl = Wtl + (size_t)(colbase + col) * 256 + kc0 * 8;
        #pragma unroll
        for (int j = 0; j < 4; ++j) {
            ((bf16x8*)Bh)[col * 33 + kc0 + j] = *(const bf16x8*)(gh + j * 8);
            ((bf16x8*)Bl)[col * 33 + kc0 + j] = *(const bf16x8*)(gl + j * 8);
        }
    }

    f32x4 acc[2][2];
    #pragma unroll
    for (int i = 0; i < 2; ++i)
        #pragma unroll
        for (int j = 0; j < 2; ++j)
            acc[i][j] = (f32x4){0.f, 0.f, 0.f, 0.f};

    __syncthreads();

    LOADA(2, 2); SB; COMPUTE(0, 0);
    LOADA(3, 0); SB; COMPUTE(1, 1);
    LOADA(4, 1); SB; COMPUTE(2, 2);
    LOADA(5, 2); SB; COMPUTE(3, 0);
    LOADA(6, 0); SB; COMPUTE(4, 1);
    LOADA(7, 1); SB; COMPUTE(5, 2);
    COMPUTE(6, 0);
    COMPUTE(7, 1);

#undef LOADA
#undef COMPUTE
#undef SB

    // ---- epilogue: D col=lane&15, row=(lane>>4)*4+r
    const int rg = lane >> 4;
    #pragma unroll
    for (int nj = 0; nj < 2; ++nj) {
        int colg = colbase + nj * 16 + rr;
        float bv = bias[colg];
        #pragma unroll
        for (int mi = 0; mi < 2; ++mi) {
            #pragma unroll
            for (int r = 0; r < 4; ++r) {
                int row = row0 + wave * 32 + mi * 16 + rg * 4 + r;
                if (row < N_NODES) {
                    float v = acc[mi][nj][r] + bv;
                    if (RELU) v = fmaxf(v, 0.f);
                    if (FINAL) {
                        out[(size_t)row * NOUT + colg] = v;
                    } else {
                        ushort hb = f2bf(v);
                        oh[(size_t)row * NOUT + colg] = hb;
                        ol[(size_t)row * NOUT + colg] = f2bf(v - bf2f(hb));
                    }
                }
            }
        }
    }
}

// ---------------------------------------------------------------- launch

extern "C" void kernel_launch(void* const* d_in, const int* in_sizes, int n_in,
                              void* d_out, int out_size, void* d_ws, size_t ws_size,
                              hipStream_t stream) {
    const float* x   = (const float*)d_in[0];
    const int*   src = (const int*)d_in[1];
    const int*   dst = (const int*)d_in[2];
    const float* Ws0 = (const float*)d_in[3];
    const float* Wn0 = (const float*)d_in[4];
    const float* b0  = (const float*)d_in[5];
    const float* Ws1 = (const float*)d_in[6];
    const float* Wn1 = (const float*)d_in[7];
    const float* b1  = (const float*)d_in[8];
    const float* Ws2 = (const float*)d_in[9];
    const float* Wn2 = (const float*)d_in[10];
    const float* b2  = (const float*)d_in[11];
    float* out = (float*)d_out;

    char* p = (char*)d_ws;
    auto alloc = [&](size_t bytes) {
        char* r = p;
        p += (bytes + 255) & ~(size_t)255;
        return r;
    };
    int*      cnt      = (int*)alloc((size_t)N_NODES * 4);
    int*      cursor   = (int*)alloc((size_t)N_NODES * 4);
    int*      rowptr   = (int*)alloc((size_t)(N_NODES + 1) * 4);
    int*      col      = (int*)alloc((size_t)N_EDGES * 4);
    int*      partials = (int*)alloc((size_t)NPART * 4);
    int*      offsets  = (int*)alloc((size_t)NPART * 4);
    uint32_t* aggh     = (uint32_t*)alloc((size_t)PADROWS * 64 * 4);
    uint32_t* aggl     = (uint32_t*)alloc((size_t)PADROWS * 64 * 4);
    ushort*   nbh0     = (ushort*)alloc((size_t)PADROWS * 128 * 2);
    ushort*   nbl0     = (ushort*)alloc((size_t)PADROWS * 128 * 2);
    ushort*   nbh1     = (ushort*)alloc((size_t)PADROWS * 128 * 2);
    ushort*   nbl1     = (ushort*)alloc((size_t)PADROWS * 128 * 2);
    short*    Wt0_hi   = (short*)alloc((size_t)128 * 256 * 2);
    short*    Wt0_lo   = (short*)alloc((size_t)128 * 256 * 2);
    short*    Wt1_hi   = (short*)alloc((size_t)128 * 256 * 2);
    short*    Wt1_lo   = (short*)alloc((size_t)128 * 256 * 2);
    short*    Wt2_hi   = (short*)alloc((size_t)64 * 256 * 2);
    short*    Wt2_lo   = (short*)alloc((size_t)64 * 256 * 2);

    // CSR build
    zero2_kernel<<<NPART, 256, 0, stream>>>(cnt, cursor);
    count_kernel<<<(N_EDGES + 255) / 256, 256, 0, stream>>>(dst, cnt);
    scan_part <<<NPART, 256, 0, stream>>>(cnt, partials);
    scan_mid  <<<1, 256, 0, stream>>>(partials, offsets);
    scan_final<<<NPART, 256, 0, stream>>>(cnt, offsets, rowptr);
    fill_kernel<<<(N_EDGES + 255) / 256, 256, 0, stream>>>(src, dst, rowptr, cursor, col);

    // weight prep + x split (single launch)
    prep_kernel<<<320 + (N_NODES * 32 + 255) / 256, 256, 0, stream>>>(
        Ws0, Wn0, Ws1, Wn1, Ws2, Wn2, x,
        Wt0_hi, Wt0_lo, Wt1_hi, Wt1_lo, Wt2_hi, Wt2_lo, nbh0, nbl0);

    const int AGB = (N_NODES + 3) / 4;        // 12500

    // layer 0
    aggregate_kernel<<<AGB, 256, 0, stream>>>(nbh0, rowptr, col, cnt, aggh, aggl);
    combine_mfma5<128, 4, true, false><<<392 * 4, 256, 0, stream>>>(
        nbh0, nbl0, (const ushort*)aggh, (const ushort*)aggl, Wt0_hi, Wt0_lo, b0, nullptr, nbh1, nbl1);
    // layer 1
    aggregate_kernel<<<AGB, 256, 0, stream>>>(nbh1, rowptr, col, cnt, aggh, aggl);
    combine_mfma5<128, 4, true, false><<<392 * 4, 256, 0, stream>>>(
        nbh1, nbl1, (const ushort*)aggh, (const ushort*)aggl, Wt1_hi, Wt1_lo, b1, nullptr, nbh0, nbl0);
    // layer 2
    aggregate_kernel<<<AGB, 256, 0, stream>>>(nbh0, rowptr, col, cnt, aggh, aggl);
    combine_mfma5<64, 2, false, true><<<392 * 2, 256, 0, stream>>>(
        nbh0, nbl0, (const ushort*)aggh, (const ushort*)aggl, Wt2_hi, Wt2_lo, b2, out, nullptr, nullptr);
}